// Round 2
// baseline (3192.175 us; speedup 1.0000x reference)
//
#include <hip/hip_runtime.h>

#define NN 20000
#define EE 320000
#define RCH 40
#define RPC 500

// ---------------- zero-init ----------------
__global__ void k_zero(float* __restrict__ p, int n) {
  int i = blockIdx.x * blockDim.x + threadIdx.x;
  if (i < n) p[i] = 0.f;
}

// ---------------- degree / edge norm ----------------
__global__ void k_deg(const int* __restrict__ ei, const float* __restrict__ ew,
                      float* __restrict__ deg) {
  int e = blockIdx.x * blockDim.x + threadIdx.x;
  if (e < EE) atomicAdd(deg + ei[EE + e], ew[e]);
}
__global__ void k_dinv(const float* __restrict__ deg, float* __restrict__ dinv,
                       float* __restrict__ dinv2) {
  int i = blockIdx.x * blockDim.x + threadIdx.x;
  if (i < NN) {
    float d = deg[i] + 1.0f;
    dinv[i]  = rsqrtf(d);
    dinv2[i] = 1.0f / d;
  }
}
__global__ void k_norm(const int* __restrict__ ei, const float* __restrict__ ew,
                       const float* __restrict__ dinv, float* __restrict__ nv) {
  int e = blockIdx.x * blockDim.x + threadIdx.x;
  if (e < EE) nv[e] = dinv[ei[e]] * ew[e] * dinv[ei[EE + e]];
}

// ---------------- fp32 tiled GEMM: C[M,N] = A[M,K] @ B[K,N] (+ fp32 bias) ----------------
__global__ __launch_bounds__(256)
void k_gemm(const float* __restrict__ A, const float* __restrict__ B,
            const float* __restrict__ bias, float* __restrict__ C,
            int M, int K, int N) {
  __shared__ float As[16][68];
  __shared__ float Bs[16][68];
  const int tid = threadIdx.x;
  const int tx = tid & 15, ty = tid >> 4;
  const int m0 = blockIdx.x * 64, n0 = blockIdx.y * 64;
  const int a_mm = tid >> 2, a_k4 = (tid & 3) << 2;   // A: 64 rows x 16 k, float4 per thread
  const int b_kk = tid >> 4, b_n4 = (tid & 15) << 2;  // B: 16 k x 64 cols, float4 per thread
  float acc[4][4] = {};
  for (int k0 = 0; k0 < K; k0 += 16) {
    float4 av = make_float4(0.f, 0.f, 0.f, 0.f);
    int arow = m0 + a_mm;
    if (arow < M) av = *(const float4*)(A + (size_t)arow * K + k0 + a_k4);
    As[a_k4 + 0][a_mm] = av.x;
    As[a_k4 + 1][a_mm] = av.y;
    As[a_k4 + 2][a_mm] = av.z;
    As[a_k4 + 3][a_mm] = av.w;
    float4 bv = *(const float4*)(B + (size_t)(k0 + b_kk) * N + n0 + b_n4);
    Bs[b_kk][b_n4 + 0] = bv.x;
    Bs[b_kk][b_n4 + 1] = bv.y;
    Bs[b_kk][b_n4 + 2] = bv.z;
    Bs[b_kk][b_n4 + 3] = bv.w;
    __syncthreads();
#pragma unroll
    for (int kk = 0; kk < 16; ++kk) {
      float a[4], b[4];
#pragma unroll
      for (int i = 0; i < 4; ++i) a[i] = As[kk][ty * 4 + i];
#pragma unroll
      for (int j = 0; j < 4; ++j) b[j] = Bs[kk][tx * 4 + j];
#pragma unroll
      for (int i = 0; i < 4; ++i)
#pragma unroll
        for (int j = 0; j < 4; ++j) acc[i][j] += a[i] * b[j];
    }
    __syncthreads();
  }
#pragma unroll
  for (int i = 0; i < 4; ++i) {
    int row = m0 + ty * 4 + i;
    if (row >= M) continue;
#pragma unroll
    for (int j = 0; j < 4; ++j) {
      int col = n0 + tx * 4 + j;
      float v = acc[i][j];
      if (bias) v += bias[col];
      C[(size_t)row * N + col] = v;
    }
  }
}

// ---------------- GCN aggregation ----------------
__global__ void k_initagg(const float* __restrict__ xw, const float* __restrict__ dinv2,
                          const float* __restrict__ bias, float* __restrict__ agg, int O) {
  int row = blockIdx.x;
  int j = blockIdx.y * blockDim.x + threadIdx.x;
  size_t idx = (size_t)row * O + j;
  agg[idx] = dinv2[row] * xw[idx] + bias[j];
}

__global__ void k_scatter(const int* __restrict__ ei, const float* __restrict__ nv,
                          const float* __restrict__ xw, float* __restrict__ agg, int O) {
  int e = blockIdx.x;
  int s = ei[e], d = ei[EE + e];
  float w = nv[e];
  const float* xs = xw + (size_t)s * O;
  float* ad = agg + (size_t)d * O;
  for (int j = threadIdx.x; j < O; j += blockDim.x) atomicAdd(ad + j, w * xs[j]);
}

// ---------------- rowwise l2norm + relu (in-place) ----------------
__global__ __launch_bounds__(256)
void k_l2relu(float* __restrict__ agg, int O) {
  int row = blockIdx.x;
  float* a = agg + (size_t)row * O;
  float ss = 0.f;
  for (int j = threadIdx.x; j < O; j += 256) { float v = a[j]; ss += v * v; }
#pragma unroll
  for (int off = 32; off > 0; off >>= 1) ss += __shfl_down(ss, off, 64);
  __shared__ float red[4];
  __shared__ float s_scale;
  int lane = threadIdx.x & 63, wave = threadIdx.x >> 6;
  if (lane == 0) red[wave] = ss;
  __syncthreads();
  if (threadIdx.x == 0) {
    float t = red[0] + red[1] + red[2] + red[3];
    s_scale = 1.0f / fmaxf(sqrtf(t), 1e-12f);
  }
  __syncthreads();
  float sc = s_scale;
  for (int j = threadIdx.x; j < O; j += 256) a[j] = fmaxf(a[j] * sc, 0.f);
}

// ---------------- reparameterize + global max/mean pooling ----------------
__global__ void k_pool_partial(const float* __restrict__ mu, const float* __restrict__ lv,
                               const float* __restrict__ eps, const float* __restrict__ beta_p,
                               float* __restrict__ pmax, float* __restrict__ psum) {
  int tx = threadIdx.x, ty = threadIdx.y;
  int col = blockIdx.x * 64 + tx;
  int by = blockIdx.y;
  float beta = beta_p[0];
  float m = -3.4e38f, s = 0.f;
  for (int i = by * RPC + ty; i < (by + 1) * RPC; i += 4) {
    size_t idx = (size_t)i * 512 + col;
    float z = mu[idx] + 0.01f * eps[idx] * expf(0.5f * beta * lv[idx]);
    m = fmaxf(m, z);
    s += z;
  }
  __shared__ float sm[4][64], su[4][64];
  sm[ty][tx] = m; su[ty][tx] = s;
  __syncthreads();
  if (ty == 0) {
    m = fmaxf(fmaxf(sm[0][tx], sm[1][tx]), fmaxf(sm[2][tx], sm[3][tx]));
    s = su[0][tx] + su[1][tx] + su[2][tx] + su[3][tx];
    pmax[(size_t)by * 512 + col] = m;
    psum[(size_t)by * 512 + col] = s;
  }
}

__global__ void k_pool_combine(const float* __restrict__ pmax, const float* __restrict__ psum,
                               float* __restrict__ out1, float* __restrict__ out2) {
  int col = threadIdx.x;  // 512 threads, 1 block
  float m = -3.4e38f, s = 0.f;
  for (int c = 0; c < RCH; ++c) {
    m = fmaxf(m, pmax[(size_t)c * 512 + col]);
    s += psum[(size_t)c * 512 + col];
  }
  out1[col] = m;
  out2[col] = s / (float)NN;
}

// ---------------- tiny decoder MLP: [1,1025] -> relu -> [1,1024] sigmoid ----------------
__global__ __launch_bounds__(1024)
void k_decoder(const float* __restrict__ out1, const float* __restrict__ out2,
               const float* __restrict__ yt,
               const float* __restrict__ Wd1, const float* __restrict__ bd1,
               const float* __restrict__ Wd2, const float* __restrict__ bd2,
               float* __restrict__ recon) {
  __shared__ float rz[1025];
  __shared__ float hdec[1025];
  int t = threadIdx.x;
  if (t < 512) { rz[t] = out1[t]; rz[512 + t] = out2[t]; }
  if (t == 0) rz[1024] = yt[0];
  __syncthreads();
  for (int n = t; n < 1025; n += 1024) {
    float acc = bd1[n];
    for (int k = 0; k < 1025; ++k) acc += rz[k] * Wd1[(size_t)k * 1025 + n];
    hdec[n] = fmaxf(acc, 0.f);
  }
  __syncthreads();
  if (t < 1024) {
    float acc = bd2[t];
    for (int k = 0; k < 1025; ++k) acc += hdec[k] * Wd2[(size_t)k * 1024 + t];
    recon[t] = 1.0f / (1.0f + expf(-acc));
  }
}

extern "C" void kernel_launch(void* const* d_in, const int* in_sizes, int n_in,
                              void* d_out, int out_size, void* d_ws, size_t ws_size,
                              hipStream_t stream) {
  const float* x    = (const float*)d_in[0];
  const int*   ei   = (const int*)d_in[1];
  const float* ew   = (const float*)d_in[2];
  const float* beta = (const float*)d_in[3];
  const float* yt   = (const float*)d_in[4];
  const float* eps  = (const float*)d_in[5];
  const float* W1   = (const float*)d_in[6];  const float* b1  = (const float*)d_in[7];
  const float* W2   = (const float*)d_in[8];  const float* b2  = (const float*)d_in[9];
  const float* W3   = (const float*)d_in[10]; const float* b3  = (const float*)d_in[11];
  const float* Wmu  = (const float*)d_in[12]; const float* bmu = (const float*)d_in[13];
  const float* Wlv  = (const float*)d_in[14]; const float* blv = (const float*)d_in[15];
  const float* Wd1  = (const float*)d_in[16]; const float* bd1 = (const float*)d_in[17];
  const float* Wd2  = (const float*)d_in[18]; const float* bd2 = (const float*)d_in[19];

  float* ws = (float*)d_ws;
  size_t off = 0;
  float* deg  = ws + off; off += NN;
  float* dinv = ws + off; off += NN;
  float* din2 = ws + off; off += NN;
  float* nv   = ws + off; off += EE;
  float* pmax = ws + off; off += RCH * 512;
  float* psum = ws + off; off += RCH * 512;
  float* out1 = ws + off; off += 512;
  float* out2 = ws + off; off += 512;
  float* bufA = ws + off; off += (size_t)NN * 1024;  // xw
  float* bufB = ws + off; off += (size_t)NN * 1024;  // agg / h (in-place)

  float* out_f  = (float*)d_out;
  float* mu_out = out_f + 1024;
  float* lv_out = out_f + 1024 + (size_t)NN * 512;

  // degrees and edge norms
  k_zero<<<(NN + 255) / 256, 256, 0, stream>>>(deg, NN);
  k_deg <<<(EE + 255) / 256, 256, 0, stream>>>(ei, ew, deg);
  k_dinv<<<(NN + 255) / 256, 256, 0, stream>>>(deg, dinv, din2);
  k_norm<<<(EE + 255) / 256, 256, 0, stream>>>(ei, ew, dinv, nv);

  // ---- GCN layer 1: 512 -> 1024 ----
  k_gemm<<<dim3(313, 16), 256, 0, stream>>>(x, W1, nullptr, bufA, NN, 512, 1024);
  k_initagg<<<dim3(NN, 4), 256, 0, stream>>>(bufA, din2, b1, bufB, 1024);
  k_scatter<<<EE, 256, 0, stream>>>(ei, nv, bufA, bufB, 1024);
  k_l2relu<<<NN, 256, 0, stream>>>(bufB, 1024);

  // ---- GCN layer 2: 1024 -> 512 ----
  k_gemm<<<dim3(313, 8), 256, 0, stream>>>(bufB, W2, nullptr, bufA, NN, 1024, 512);
  k_initagg<<<dim3(NN, 2), 256, 0, stream>>>(bufA, din2, b2, bufB, 512);
  k_scatter<<<EE, 256, 0, stream>>>(ei, nv, bufA, bufB, 512);
  k_l2relu<<<NN, 256, 0, stream>>>(bufB, 512);

  // ---- GCN layer 3: 512 -> 256 ----
  k_gemm<<<dim3(313, 4), 256, 0, stream>>>(bufB, W3, nullptr, bufA, NN, 512, 256);
  k_initagg<<<dim3(NN, 1), 256, 0, stream>>>(bufA, din2, b3, bufB, 256);
  k_scatter<<<EE, 256, 0, stream>>>(ei, nv, bufA, bufB, 256);
  k_l2relu<<<NN, 256, 0, stream>>>(bufB, 256);

  // ---- VAE heads: mu, logvar directly into d_out (fp32) ----
  k_gemm<<<dim3(313, 8), 256, 0, stream>>>(bufB, Wmu, bmu, mu_out, NN, 256, 512);
  k_gemm<<<dim3(313, 8), 256, 0, stream>>>(bufB, Wlv, blv, lv_out, NN, 256, 512);

  // ---- reparameterize + pooling ----
  k_pool_partial<<<dim3(8, RCH), dim3(64, 4), 0, stream>>>(mu_out, lv_out, eps, beta, pmax, psum);
  k_pool_combine<<<1, 512, 0, stream>>>(pmax, psum, out1, out2);

  // ---- decoder ----
  k_decoder<<<1, 1024, 0, stream>>>(out1, out2, yt, Wd1, bd1, Wd2, bd2, out_f);
}

// Round 3
// 1706.327 us; speedup vs baseline: 1.8708x; 1.8708x over previous
//
#include <hip/hip_runtime.h>

#define NN 20000
#define EE 320000
#define RCH 40
#define RPC 500

// ---------------- zero-init (int) ----------------
__global__ void k_zeroi(int* __restrict__ p, int n) {
  int i = blockIdx.x * blockDim.x + threadIdx.x;
  if (i < n) p[i] = 0;
}

// ---------------- CSR build: count / scan / fill ----------------
__global__ void k_count(const int* __restrict__ ei, int* __restrict__ counts) {
  int e = blockIdx.x * blockDim.x + threadIdx.x;
  if (e < EE) atomicAdd(counts + ei[EE + e], 1);
}

// one block, 256 threads: exclusive scan of counts[NN] -> rowptr[NN+1], cursor=rowptr
__global__ __launch_bounds__(256)
void k_scan(const int* __restrict__ counts, int* __restrict__ rowptr, int* __restrict__ cursor) {
  const int CHUNK = (NN + 255) / 256;  // 79
  int t = threadIdx.x;
  int lo = t * CHUNK, hi = min(lo + CHUNK, NN);
  int s = 0;
  for (int i = lo; i < hi; ++i) s += counts[i];
  __shared__ int tsum[256];
  tsum[t] = s;
  __syncthreads();
  if (t == 0) {
    int run = 0;
    for (int i = 0; i < 256; ++i) { int v = tsum[i]; tsum[i] = run; run += v; }
  }
  __syncthreads();
  int run = tsum[t];
  for (int i = lo; i < hi; ++i) {
    rowptr[i] = run;
    cursor[i] = run;
    run += counts[i];
  }
  if (t == 255) rowptr[NN] = EE;
}

__global__ void k_fill(const int* __restrict__ ei, const float* __restrict__ ew,
                       int* __restrict__ cursor, int* __restrict__ colsrc,
                       float* __restrict__ ecw) {
  int e = blockIdx.x * blockDim.x + threadIdx.x;
  if (e < EE) {
    int d = ei[EE + e];
    int pos = atomicAdd(cursor + d, 1);
    colsrc[pos] = ei[e];
    ecw[pos] = ew[e];
  }
}

// per-row degree from CSR -> dinv, dinv2
__global__ void k_degcsr(const int* __restrict__ rowptr, const float* __restrict__ ecw,
                         float* __restrict__ dinv, float* __restrict__ dinv2) {
  int i = blockIdx.x * blockDim.x + threadIdx.x;
  if (i < NN) {
    float s = 0.f;
    for (int e = rowptr[i]; e < rowptr[i + 1]; ++e) s += ecw[e];
    float d = s + 1.0f;
    dinv[i] = rsqrtf(d);
    dinv2[i] = 1.0f / d;
  }
}

// ---------------- fp32 tiled GEMM: C[M,N] = A[M,K] @ B[K,N] (+ fp32 bias) ----------------
__global__ __launch_bounds__(256)
void k_gemm(const float* __restrict__ A, const float* __restrict__ B,
            const float* __restrict__ bias, float* __restrict__ C,
            int M, int K, int N) {
  __shared__ float As[16][68];
  __shared__ float Bs[16][68];
  const int tid = threadIdx.x;
  const int tx = tid & 15, ty = tid >> 4;
  const int m0 = blockIdx.x * 64, n0 = blockIdx.y * 64;
  const int a_mm = tid >> 2, a_k4 = (tid & 3) << 2;
  const int b_kk = tid >> 4, b_n4 = (tid & 15) << 2;
  float acc[4][4] = {};
  for (int k0 = 0; k0 < K; k0 += 16) {
    float4 av = make_float4(0.f, 0.f, 0.f, 0.f);
    int arow = m0 + a_mm;
    if (arow < M) av = *(const float4*)(A + (size_t)arow * K + k0 + a_k4);
    As[a_k4 + 0][a_mm] = av.x;
    As[a_k4 + 1][a_mm] = av.y;
    As[a_k4 + 2][a_mm] = av.z;
    As[a_k4 + 3][a_mm] = av.w;
    float4 bv = *(const float4*)(B + (size_t)(k0 + b_kk) * N + n0 + b_n4);
    Bs[b_kk][b_n4 + 0] = bv.x;
    Bs[b_kk][b_n4 + 1] = bv.y;
    Bs[b_kk][b_n4 + 2] = bv.z;
    Bs[b_kk][b_n4 + 3] = bv.w;
    __syncthreads();
#pragma unroll
    for (int kk = 0; kk < 16; ++kk) {
      float a[4], b[4];
#pragma unroll
      for (int i = 0; i < 4; ++i) a[i] = As[kk][ty * 4 + i];
#pragma unroll
      for (int j = 0; j < 4; ++j) b[j] = Bs[kk][tx * 4 + j];
#pragma unroll
      for (int i = 0; i < 4; ++i)
#pragma unroll
        for (int j = 0; j < 4; ++j) acc[i][j] += a[i] * b[j];
    }
    __syncthreads();
  }
#pragma unroll
  for (int i = 0; i < 4; ++i) {
    int row = m0 + ty * 4 + i;
    if (row >= M) continue;
#pragma unroll
    for (int j = 0; j < 4; ++j) {
      int col = n0 + tx * 4 + j;
      float v = acc[i][j];
      if (bias) v += bias[col];
      C[(size_t)row * N + col] = v;
    }
  }
}

// ---------------- fused CSR gather + self-loop + bias + l2norm + relu ----------------
// one block (256 threads) per destination row; CPT columns per thread (O = CPT*256)
template <int CPT>
__global__ __launch_bounds__(256)
void k_gather(const int* __restrict__ rowptr, const int* __restrict__ colsrc,
              const float* __restrict__ ecw, const float* __restrict__ dinv,
              const float* __restrict__ dinv2, const float* __restrict__ xw,
              const float* __restrict__ bias, float* __restrict__ h) {
  const int O = CPT * 256;
  const int row = blockIdx.x;
  const int tid = threadIdx.x;
  const float dv = dinv[row];
  const float dv2 = dinv2[row];

  float acc[CPT];
  const float* xr = xw + (size_t)row * O;
#pragma unroll
  for (int k = 0; k < CPT; ++k) {
    int col = tid + k * 256;
    acc[k] = dv2 * xr[col] + bias[col];
  }

  __shared__ int s_src[256];
  __shared__ float s_w[256];
  const int e0 = rowptr[row], e1 = rowptr[row + 1];
  for (int base = e0; base < e1; base += 256) {
    int cnt = min(256, e1 - base);
    if (tid < cnt) {
      int s = colsrc[base + tid];
      s_src[tid] = s;
      s_w[tid] = dinv[s] * ecw[base + tid] * dv;
    }
    __syncthreads();
    for (int e = 0; e < cnt; ++e) {
      const float w = s_w[e];
      const float* xs = xw + (size_t)s_src[e] * O;
#pragma unroll
      for (int k = 0; k < CPT; ++k) acc[k] += w * xs[tid + k * 256];
    }
    __syncthreads();
  }

  // l2 norm + relu
  float ss = 0.f;
#pragma unroll
  for (int k = 0; k < CPT; ++k) ss += acc[k] * acc[k];
#pragma unroll
  for (int off = 32; off > 0; off >>= 1) ss += __shfl_down(ss, off, 64);
  __shared__ float red[4];
  __shared__ float s_scale;
  int lane = tid & 63, wave = tid >> 6;
  if (lane == 0) red[wave] = ss;
  __syncthreads();
  if (tid == 0) {
    float t = red[0] + red[1] + red[2] + red[3];
    s_scale = 1.0f / fmaxf(sqrtf(t), 1e-12f);
  }
  __syncthreads();
  const float sc = s_scale;
  float* hr = h + (size_t)row * O;
#pragma unroll
  for (int k = 0; k < CPT; ++k) hr[tid + k * 256] = fmaxf(acc[k] * sc, 0.f);
}

// ---------------- reparameterize + global max/mean pooling ----------------
__global__ void k_pool_partial(const float* __restrict__ mu, const float* __restrict__ lv,
                               const float* __restrict__ eps, const float* __restrict__ beta_p,
                               float* __restrict__ pmax, float* __restrict__ psum) {
  int tx = threadIdx.x, ty = threadIdx.y;
  int col = blockIdx.x * 64 + tx;
  int by = blockIdx.y;
  float beta = beta_p[0];
  float m = -3.4e38f, s = 0.f;
  for (int i = by * RPC + ty; i < (by + 1) * RPC; i += 4) {
    size_t idx = (size_t)i * 512 + col;
    float z = mu[idx] + 0.01f * eps[idx] * expf(0.5f * beta * lv[idx]);
    m = fmaxf(m, z);
    s += z;
  }
  __shared__ float sm[4][64], su[4][64];
  sm[ty][tx] = m; su[ty][tx] = s;
  __syncthreads();
  if (ty == 0) {
    m = fmaxf(fmaxf(sm[0][tx], sm[1][tx]), fmaxf(sm[2][tx], sm[3][tx]));
    s = su[0][tx] + su[1][tx] + su[2][tx] + su[3][tx];
    pmax[(size_t)by * 512 + col] = m;
    psum[(size_t)by * 512 + col] = s;
  }
}

__global__ void k_pool_combine(const float* __restrict__ pmax, const float* __restrict__ psum,
                               float* __restrict__ out1, float* __restrict__ out2) {
  int col = threadIdx.x;
  float m = -3.4e38f, s = 0.f;
  for (int c = 0; c < RCH; ++c) {
    m = fmaxf(m, pmax[(size_t)c * 512 + col]);
    s += psum[(size_t)c * 512 + col];
  }
  out1[col] = m;
  out2[col] = s / (float)NN;
}

// ---------------- tiny decoder MLP ----------------
__global__ __launch_bounds__(1024)
void k_decoder(const float* __restrict__ out1, const float* __restrict__ out2,
               const float* __restrict__ yt,
               const float* __restrict__ Wd1, const float* __restrict__ bd1,
               const float* __restrict__ Wd2, const float* __restrict__ bd2,
               float* __restrict__ recon) {
  __shared__ float rz[1025];
  __shared__ float hdec[1025];
  int t = threadIdx.x;
  if (t < 512) { rz[t] = out1[t]; rz[512 + t] = out2[t]; }
  if (t == 0) rz[1024] = yt[0];
  __syncthreads();
  for (int n = t; n < 1025; n += 1024) {
    float acc = bd1[n];
    for (int k = 0; k < 1025; ++k) acc += rz[k] * Wd1[(size_t)k * 1025 + n];
    hdec[n] = fmaxf(acc, 0.f);
  }
  __syncthreads();
  if (t < 1024) {
    float acc = bd2[t];
    for (int k = 0; k < 1025; ++k) acc += hdec[k] * Wd2[(size_t)k * 1024 + t];
    recon[t] = 1.0f / (1.0f + expf(-acc));
  }
}

extern "C" void kernel_launch(void* const* d_in, const int* in_sizes, int n_in,
                              void* d_out, int out_size, void* d_ws, size_t ws_size,
                              hipStream_t stream) {
  const float* x    = (const float*)d_in[0];
  const int*   ei   = (const int*)d_in[1];
  const float* ew   = (const float*)d_in[2];
  const float* beta = (const float*)d_in[3];
  const float* yt   = (const float*)d_in[4];
  const float* eps  = (const float*)d_in[5];
  const float* W1   = (const float*)d_in[6];  const float* b1  = (const float*)d_in[7];
  const float* W2   = (const float*)d_in[8];  const float* b2  = (const float*)d_in[9];
  const float* W3   = (const float*)d_in[10]; const float* b3  = (const float*)d_in[11];
  const float* Wmu  = (const float*)d_in[12]; const float* bmu = (const float*)d_in[13];
  const float* Wlv  = (const float*)d_in[14]; const float* blv = (const float*)d_in[15];
  const float* Wd1  = (const float*)d_in[16]; const float* bd1 = (const float*)d_in[17];
  const float* Wd2  = (const float*)d_in[18]; const float* bd2 = (const float*)d_in[19];

  char* wsb = (char*)d_ws;
  size_t off = 0;
  auto alloc_f = [&](size_t n) { float* p = (float*)(wsb + off); off += n * sizeof(float); return p; };
  auto alloc_i = [&](size_t n) { int* p = (int*)(wsb + off); off += n * sizeof(int); return p; };

  int* counts  = alloc_i(NN);
  int* rowptr  = alloc_i(NN + 1);
  int* cursor  = alloc_i(NN);
  int* colsrc  = alloc_i(EE);
  float* ecw   = alloc_f(EE);
  float* dinv  = alloc_f(NN);
  float* din2  = alloc_f(NN);
  float* pmax  = alloc_f(RCH * 512);
  float* psum  = alloc_f(RCH * 512);
  float* out1  = alloc_f(512);
  float* out2  = alloc_f(512);
  float* bufA  = alloc_f((size_t)NN * 1024);  // xw
  float* bufB  = alloc_f((size_t)NN * 1024);  // h (fused gather output)

  float* out_f  = (float*)d_out;
  float* mu_out = out_f + 1024;
  float* lv_out = out_f + 1024 + (size_t)NN * 512;

  // ---- CSR build + degree norms ----
  k_zeroi<<<(NN + 255) / 256, 256, 0, stream>>>(counts, NN);
  k_count<<<(EE + 255) / 256, 256, 0, stream>>>(ei, counts);
  k_scan<<<1, 256, 0, stream>>>(counts, rowptr, cursor);
  k_fill<<<(EE + 255) / 256, 256, 0, stream>>>(ei, ew, cursor, colsrc, ecw);
  k_degcsr<<<(NN + 255) / 256, 256, 0, stream>>>(rowptr, ecw, dinv, din2);

  // ---- GCN layer 1: 512 -> 1024 ----
  k_gemm<<<dim3(313, 16), 256, 0, stream>>>(x, W1, nullptr, bufA, NN, 512, 1024);
  k_gather<4><<<NN, 256, 0, stream>>>(rowptr, colsrc, ecw, dinv, din2, bufA, b1, bufB);

  // ---- GCN layer 2: 1024 -> 512 ----
  k_gemm<<<dim3(313, 8), 256, 0, stream>>>(bufB, W2, nullptr, bufA, NN, 1024, 512);
  k_gather<2><<<NN, 256, 0, stream>>>(rowptr, colsrc, ecw, dinv, din2, bufA, b2, bufB);

  // ---- GCN layer 3: 512 -> 256 ----
  k_gemm<<<dim3(313, 4), 256, 0, stream>>>(bufB, W3, nullptr, bufA, NN, 512, 256);
  k_gather<1><<<NN, 256, 0, stream>>>(rowptr, colsrc, ecw, dinv, din2, bufA, b3, bufB);

  // ---- VAE heads: mu, logvar directly into d_out (fp32) ----
  k_gemm<<<dim3(313, 8), 256, 0, stream>>>(bufB, Wmu, bmu, mu_out, NN, 256, 512);
  k_gemm<<<dim3(313, 8), 256, 0, stream>>>(bufB, Wlv, blv, lv_out, NN, 256, 512);

  // ---- reparameterize + pooling ----
  k_pool_partial<<<dim3(8, RCH), dim3(64, 4), 0, stream>>>(mu_out, lv_out, eps, beta, pmax, psum);
  k_pool_combine<<<1, 512, 0, stream>>>(pmax, psum, out1, out2);

  // ---- decoder ----
  k_decoder<<<1, 1024, 0, stream>>>(out1, out2, yt, Wd1, bd1, Wd2, bd2, out_f);
}

// Round 4
// 954.720 us; speedup vs baseline: 3.3436x; 1.7873x over previous
//
#include <hip/hip_runtime.h>

#define NN 20000
#define EE 320000
#define RCH 40
#define RPC 500
#define MPAD 20096  // NN padded to multiple of 128

typedef unsigned short u16;
typedef unsigned int u32;
typedef __attribute__((ext_vector_type(8))) short short8;
typedef __attribute__((ext_vector_type(4))) float f32x4;

// ---------------- bf16 helpers ----------------
__device__ inline float bf16lo(u32 u) { return __uint_as_float(u << 16); }
__device__ inline float bf16hi(u32 u) { return __uint_as_float(u & 0xffff0000u); }
__device__ inline u16 f2b(float f) {
  u32 u = __float_as_uint(f);
  u += 0x7fffu + ((u >> 16) & 1u);
  return (u16)(u >> 16);
}
__device__ inline u32 pack2(float a, float b) {
  return (u32)f2b(a) | ((u32)f2b(b) << 16);
}

__device__ inline void gload16(const void* g, void* l) {
  __builtin_amdgcn_global_load_lds(
      (const __attribute__((address_space(1))) void*)g,
      (__attribute__((address_space(3))) void*)l, 16, 0, 0);
}

// ---------------- zero-init (int) ----------------
__global__ void k_zeroi(int* __restrict__ p, int n) {
  int i = blockIdx.x * blockDim.x + threadIdx.x;
  if (i < n) p[i] = 0;
}

// ---------------- fp32 -> bf16 cast (pairs) ----------------
__global__ void k_f2b2(const float* __restrict__ in, u16* __restrict__ out, int npairs) {
  for (int i = blockIdx.x * blockDim.x + threadIdx.x; i < npairs; i += gridDim.x * blockDim.x) {
    float2 v = *(const float2*)(in + 2 * i);
    ((u32*)out)[i] = pack2(v.x, v.y);
  }
}

// ---------------- weight transpose + cast: W[K x N] fp32 -> WT[N x K] bf16 ----------------
__global__ void k_wt(const float* __restrict__ W, u16* __restrict__ WT, int K, int N) {
  int k = blockIdx.y * 256 + threadIdx.x;
  int n = blockIdx.x;
  WT[(size_t)n * K + k] = f2b(W[(size_t)k * N + n]);
}

// ---------------- CSR build: count / scan / fill ----------------
__global__ void k_count(const int* __restrict__ ei, int* __restrict__ counts) {
  int e = blockIdx.x * blockDim.x + threadIdx.x;
  if (e < EE) atomicAdd(counts + ei[EE + e], 1);
}

__global__ __launch_bounds__(256)
void k_scan(const int* __restrict__ counts, int* __restrict__ rowptr, int* __restrict__ cursor) {
  const int CHUNK = (NN + 255) / 256;
  int t = threadIdx.x;
  int lo = t * CHUNK, hi = min(lo + CHUNK, NN);
  int s = 0;
  for (int i = lo; i < hi; ++i) s += counts[i];
  __shared__ int tsum[256];
  tsum[t] = s;
  __syncthreads();
  if (t == 0) {
    int run = 0;
    for (int i = 0; i < 256; ++i) { int v = tsum[i]; tsum[i] = run; run += v; }
  }
  __syncthreads();
  int run = tsum[t];
  for (int i = lo; i < hi; ++i) {
    rowptr[i] = run;
    cursor[i] = run;
    run += counts[i];
  }
  if (t == 255) rowptr[NN] = EE;
}

__global__ void k_fill(const int* __restrict__ ei, const float* __restrict__ ew,
                       int* __restrict__ cursor, int* __restrict__ colsrc,
                       float* __restrict__ ecw) {
  int e = blockIdx.x * blockDim.x + threadIdx.x;
  if (e < EE) {
    int d = ei[EE + e];
    int pos = atomicAdd(cursor + d, 1);
    colsrc[pos] = ei[e];
    ecw[pos] = ew[e];
  }
}

__global__ void k_degcsr(const int* __restrict__ rowptr, const float* __restrict__ ecw,
                         float* __restrict__ dinv, float* __restrict__ dinv2) {
  int i = blockIdx.x * blockDim.x + threadIdx.x;
  if (i < NN) {
    float s = 0.f;
    for (int e = rowptr[i]; e < rowptr[i + 1]; ++e) s += ecw[e];
    float d = s + 1.0f;
    dinv[i] = rsqrtf(d);
    dinv2[i] = 1.0f / d;
  }
}

// ---------------- bf16 MFMA GEMM: C[M,N] = A[M,K] @ BT[N,K]^T (+bias) ----------------
// 128x128 tile, BK=32, 256 threads = 4 waves in 2x2, each wave 4x4 of 16x16x32 MFMA.
template <bool STORE_BF16, bool HAS_BIAS>
__global__ __launch_bounds__(256)
void k_mfma(const u16* __restrict__ A, const u16* __restrict__ BT,
            const float* __restrict__ bias, void* __restrict__ C,
            int M, int K, int N) {
  __shared__ u16 Asm[128 * 32];
  __shared__ u16 Bsm[128 * 32];
  const int tid = threadIdx.x;
  const int m0 = blockIdx.x * 128;
  const int n0 = blockIdx.y * 128;
  const int lane = tid & 63;
  const int wave = tid >> 6;
  const int wm = (wave >> 1) * 64;
  const int wn = (wave & 1) * 64;
  const int qm = lane & 15;
  const int quad = lane >> 4;

  f32x4 acc[4][4];
#pragma unroll
  for (int i = 0; i < 4; ++i)
#pragma unroll
    for (int j = 0; j < 4; ++j) acc[i][j] = (f32x4){0.f, 0.f, 0.f, 0.f};

  for (int k0 = 0; k0 < K; k0 += 32) {
#pragma unroll
    for (int h = 0; h < 2; ++h) {
      int c = h * 256 + tid;          // chunk id 0..511, 16B each
      int row = c >> 2, kc = c & 3;   // row 0..127, k-chunk of 8 bf16
      gload16(A + (size_t)(m0 + row) * K + k0 + kc * 8, Asm + c * 8);
      gload16(BT + (size_t)(n0 + row) * K + k0 + kc * 8, Bsm + c * 8);
    }
    __syncthreads();
    short8 af[4], bfr[4];
#pragma unroll
    for (int i = 0; i < 4; ++i)
      af[i] = *(const short8*)(Asm + (wm + i * 16 + qm) * 32 + quad * 8);
#pragma unroll
    for (int j = 0; j < 4; ++j)
      bfr[j] = *(const short8*)(Bsm + (wn + j * 16 + qm) * 32 + quad * 8);
#pragma unroll
    for (int i = 0; i < 4; ++i)
#pragma unroll
      for (int j = 0; j < 4; ++j)
        acc[i][j] = __builtin_amdgcn_mfma_f32_16x16x32_bf16(af[i], bfr[j], acc[i][j], 0, 0, 0);
    __syncthreads();
  }

#pragma unroll
  for (int i = 0; i < 4; ++i) {
#pragma unroll
    for (int r = 0; r < 4; ++r) {
      int row = m0 + wm + i * 16 + quad * 4 + r;
      if (row >= M) continue;
#pragma unroll
      for (int j = 0; j < 4; ++j) {
        int col = n0 + wn + j * 16 + qm;
        float v = acc[i][j][r];
        if (HAS_BIAS) v += bias[col];
        if (STORE_BF16) ((u16*)C)[(size_t)row * N + col] = f2b(v);
        else ((float*)C)[(size_t)row * N + col] = v;
      }
    }
  }
}

// ---------------- fused CSR gather (bf16 in/out), O = 2*NT ----------------
// PRE: agg only (self-loop, no bias/norm). !PRE: + bias + l2norm + relu.
template <int NT, bool PRE>
__global__ __launch_bounds__(NT)
void k_gather(const int* __restrict__ rowptr, const int* __restrict__ colsrc,
              const float* __restrict__ ecw, const float* __restrict__ dinv,
              const float* __restrict__ dinv2, const u16* __restrict__ xw,
              const float* __restrict__ bias, u16* __restrict__ h) {
  const int O = 2 * NT;
  const int row = blockIdx.x;
  const int tid = threadIdx.x;
  const float dv = dinv[row], dv2 = dinv2[row];
  u32 u = ((const u32*)(xw + (size_t)row * O))[tid];
  float a0 = dv2 * bf16lo(u);
  float a1 = dv2 * bf16hi(u);
  if (!PRE) { a0 += bias[2 * tid]; a1 += bias[2 * tid + 1]; }

  __shared__ int s_src[NT];
  __shared__ float s_w[NT];
  const int e0 = rowptr[row], e1 = rowptr[row + 1];
  for (int base = e0; base < e1; base += NT) {
    int cnt = min(NT, e1 - base);
    __syncthreads();
    if (tid < cnt) {
      int s = colsrc[base + tid];
      s_src[tid] = s;
      s_w[tid] = dinv[s] * ecw[base + tid] * dv;
    }
    __syncthreads();
    for (int e = 0; e < cnt; ++e) {
      float w = s_w[e];
      u32 v = ((const u32*)(xw + (size_t)s_src[e] * O))[tid];
      a0 += w * bf16lo(v);
      a1 += w * bf16hi(v);
    }
  }

  if (PRE) {
    ((u32*)h)[(size_t)row * NT + tid] = pack2(a0, a1);
    return;
  }
  float ss = a0 * a0 + a1 * a1;
#pragma unroll
  for (int off = 32; off > 0; off >>= 1) ss += __shfl_down(ss, off, 64);
  __shared__ float red[NT / 64];
  __shared__ float s_scale;
  if ((tid & 63) == 0) red[tid >> 6] = ss;
  __syncthreads();
  if (tid == 0) {
    float t = 0.f;
#pragma unroll
    for (int i = 0; i < NT / 64; ++i) t += red[i];
    s_scale = 1.0f / fmaxf(sqrtf(t), 1e-12f);
  }
  __syncthreads();
  float sc = s_scale;
  ((u32*)h)[(size_t)row * NT + tid] = pack2(fmaxf(a0 * sc, 0.f), fmaxf(a1 * sc, 0.f));
}

// ---------------- rowwise l2norm + relu, bf16 in/out, O=1024 ----------------
__global__ __launch_bounds__(256)
void k_l2relu(const u16* __restrict__ t, u16* __restrict__ h) {
  const int row = blockIdx.x;
  const int tid = threadIdx.x;
  const u32* tr = (const u32*)(t + (size_t)row * 1024);
  u32 u0 = tr[tid], u1 = tr[256 + tid];
  float a0 = bf16lo(u0), a1 = bf16hi(u0), a2 = bf16lo(u1), a3 = bf16hi(u1);
  float ss = a0 * a0 + a1 * a1 + a2 * a2 + a3 * a3;
#pragma unroll
  for (int off = 32; off > 0; off >>= 1) ss += __shfl_down(ss, off, 64);
  __shared__ float red[4];
  __shared__ float s_scale;
  if ((tid & 63) == 0) red[tid >> 6] = ss;
  __syncthreads();
  if (tid == 0) {
    float s = red[0] + red[1] + red[2] + red[3];
    s_scale = 1.0f / fmaxf(sqrtf(s), 1e-12f);
  }
  __syncthreads();
  float sc = s_scale;
  u32* hr = (u32*)(h + (size_t)row * 1024);
  hr[tid]       = pack2(fmaxf(a0 * sc, 0.f), fmaxf(a1 * sc, 0.f));
  hr[256 + tid] = pack2(fmaxf(a2 * sc, 0.f), fmaxf(a3 * sc, 0.f));
}

// ---------------- reparameterize + global max/mean pooling ----------------
__global__ void k_pool_partial(const float* __restrict__ mu, const float* __restrict__ lv,
                               const float* __restrict__ eps, const float* __restrict__ beta_p,
                               float* __restrict__ pmax, float* __restrict__ psum) {
  int tx = threadIdx.x, ty = threadIdx.y;
  int col = blockIdx.x * 64 + tx;
  int by = blockIdx.y;
  float beta = beta_p[0];
  float m = -3.4e38f, s = 0.f;
  for (int i = by * RPC + ty; i < (by + 1) * RPC; i += 4) {
    size_t idx = (size_t)i * 512 + col;
    float z = mu[idx] + 0.01f * eps[idx] * expf(0.5f * beta * lv[idx]);
    m = fmaxf(m, z);
    s += z;
  }
  __shared__ float sm[4][64], su[4][64];
  sm[ty][tx] = m; su[ty][tx] = s;
  __syncthreads();
  if (ty == 0) {
    m = fmaxf(fmaxf(sm[0][tx], sm[1][tx]), fmaxf(sm[2][tx], sm[3][tx]));
    s = su[0][tx] + su[1][tx] + su[2][tx] + su[3][tx];
    pmax[(size_t)by * 512 + col] = m;
    psum[(size_t)by * 512 + col] = s;
  }
}

__global__ void k_pool_combine(const float* __restrict__ pmax, const float* __restrict__ psum,
                               float* __restrict__ out1, float* __restrict__ out2) {
  int col = threadIdx.x;
  float m = -3.4e38f, s = 0.f;
  for (int c = 0; c < RCH; ++c) {
    m = fmaxf(m, pmax[(size_t)c * 512 + col]);
    s += psum[(size_t)c * 512 + col];
  }
  out1[col] = m;
  out2[col] = s / (float)NN;
}

// ---------------- tiny decoder MLP ----------------
__global__ __launch_bounds__(1024)
void k_decoder(const float* __restrict__ out1, const float* __restrict__ out2,
               const float* __restrict__ yt,
               const float* __restrict__ Wd1, const float* __restrict__ bd1,
               const float* __restrict__ Wd2, const float* __restrict__ bd2,
               float* __restrict__ recon) {
  __shared__ float rz[1025];
  __shared__ float hdec[1025];
  int t = threadIdx.x;
  if (t < 512) { rz[t] = out1[t]; rz[512 + t] = out2[t]; }
  if (t == 0) rz[1024] = yt[0];
  __syncthreads();
  for (int n = t; n < 1025; n += 1024) {
    float acc = bd1[n];
    for (int k = 0; k < 1025; ++k) acc += rz[k] * Wd1[(size_t)k * 1025 + n];
    hdec[n] = fmaxf(acc, 0.f);
  }
  __syncthreads();
  if (t < 1024) {
    float acc = bd2[t];
    for (int k = 0; k < 1025; ++k) acc += hdec[k] * Wd2[(size_t)k * 1024 + t];
    recon[t] = 1.0f / (1.0f + expf(-acc));
  }
}

extern "C" void kernel_launch(void* const* d_in, const int* in_sizes, int n_in,
                              void* d_out, int out_size, void* d_ws, size_t ws_size,
                              hipStream_t stream) {
  const float* x    = (const float*)d_in[0];
  const int*   ei   = (const int*)d_in[1];
  const float* ew   = (const float*)d_in[2];
  const float* beta = (const float*)d_in[3];
  const float* yt   = (const float*)d_in[4];
  const float* eps  = (const float*)d_in[5];
  const float* W1   = (const float*)d_in[6];  const float* b1  = (const float*)d_in[7];
  const float* W2   = (const float*)d_in[8];  const float* b2  = (const float*)d_in[9];
  const float* W3   = (const float*)d_in[10]; const float* b3  = (const float*)d_in[11];
  const float* Wmu  = (const float*)d_in[12]; const float* bmu = (const float*)d_in[13];
  const float* Wlv  = (const float*)d_in[14]; const float* blv = (const float*)d_in[15];
  const float* Wd1  = (const float*)d_in[16]; const float* bd1 = (const float*)d_in[17];
  const float* Wd2  = (const float*)d_in[18]; const float* bd2 = (const float*)d_in[19];

  char* wsb = (char*)d_ws;
  size_t off = 0;
  auto alloc_f = [&](size_t n) { float* p = (float*)(wsb + off); off += n * sizeof(float); return p; };
  auto alloc_i = [&](size_t n) { int* p = (int*)(wsb + off); off += n * sizeof(int); return p; };
  auto alloc_h = [&](size_t n) { u16* p = (u16*)(wsb + off); off += ((n * 2 + 3) & ~(size_t)3); return p; };

  int* counts  = alloc_i(NN);
  int* rowptr  = alloc_i(NN + 1);
  int* cursor  = alloc_i(NN);
  int* colsrc  = alloc_i(EE);
  float* ecw   = alloc_f(EE);
  float* dinv  = alloc_f(NN);
  float* din2  = alloc_f(NN);
  float* pmax  = alloc_f(RCH * 512);
  float* psum  = alloc_f(RCH * 512);
  float* out1  = alloc_f(512);
  float* out2  = alloc_f(512);
  u16* W1T  = alloc_h(1024 * 512);
  u16* W2T  = alloc_h(512 * 1024);
  u16* W3T  = alloc_h(256 * 512);
  u16* WmuT = alloc_h(512 * 256);
  u16* WlvT = alloc_h(512 * 256);
  u16* xb   = alloc_h((size_t)MPAD * 512);   // x bf16; later reused as h3 (256)
  u16* aggx = alloc_h((size_t)MPAD * 512);   // pre-aggregated x
  u16* bufT = alloc_h((size_t)MPAD * 1024);  // t1; later z2 (512)
  u16* bufH = alloc_h((size_t)MPAD * 1024);  // h1; later z3 (256)
  u16* h2   = alloc_h((size_t)MPAD * 512);
  u16* h3   = xb;
  u16* z2   = bufT;
  u16* z3   = bufH;

  float* out_f  = (float*)d_out;
  float* mu_out = out_f + 1024;
  float* lv_out = out_f + 1024 + (size_t)NN * 512;

  const int MT = (NN + 127) / 128;  // 157

  // ---- casts / transposes ----
  k_f2b2<<<4096, 256, 0, stream>>>(x, xb, NN * 512 / 2);
  k_wt<<<dim3(1024, 2), 256, 0, stream>>>(W1, W1T, 512, 1024);
  k_wt<<<dim3(512, 4), 256, 0, stream>>>(W2, W2T, 1024, 512);
  k_wt<<<dim3(256, 2), 256, 0, stream>>>(W3, W3T, 512, 256);
  k_wt<<<dim3(512, 1), 256, 0, stream>>>(Wmu, WmuT, 256, 512);
  k_wt<<<dim3(512, 1), 256, 0, stream>>>(Wlv, WlvT, 256, 512);

  // ---- CSR build + degree norms ----
  k_zeroi<<<(NN + 255) / 256, 256, 0, stream>>>(counts, NN);
  k_count<<<(EE + 255) / 256, 256, 0, stream>>>(ei, counts);
  k_scan<<<1, 256, 0, stream>>>(counts, rowptr, cursor);
  k_fill<<<(EE + 255) / 256, 256, 0, stream>>>(ei, ew, cursor, colsrc, ecw);
  k_degcsr<<<(NN + 255) / 256, 256, 0, stream>>>(rowptr, ecw, dinv, din2);

  // ---- layer 1: aggregate x first (linearity), then GEMM+bias, then l2relu ----
  k_gather<256, true><<<NN, 256, 0, stream>>>(rowptr, colsrc, ecw, dinv, din2, xb, nullptr, aggx);
  k_mfma<true, true><<<dim3(MT, 8), 256, 0, stream>>>(aggx, W1T, b1, bufT, NN, 512, 1024);
  k_l2relu<<<NN, 256, 0, stream>>>(bufT, bufH);

  // ---- layer 2: GEMM then fused gather+bias+l2relu ----
  k_mfma<true, false><<<dim3(MT, 4), 256, 0, stream>>>(bufH, W2T, nullptr, z2, NN, 1024, 512);
  k_gather<256, false><<<NN, 256, 0, stream>>>(rowptr, colsrc, ecw, dinv, din2, z2, b2, h2);

  // ---- layer 3 ----
  k_mfma<true, false><<<dim3(MT, 2), 256, 0, stream>>>(h2, W3T, nullptr, z3, NN, 512, 256);
  k_gather<128, false><<<NN, 128, 0, stream>>>(rowptr, colsrc, ecw, dinv, din2, z3, b3, h3);

  // ---- VAE heads: fp32 out with bias ----
  k_mfma<false, true><<<dim3(MT, 4), 256, 0, stream>>>(h3, WmuT, bmu, mu_out, NN, 256, 512);
  k_mfma<false, true><<<dim3(MT, 4), 256, 0, stream>>>(h3, WlvT, blv, lv_out, NN, 256, 512);

  // ---- reparameterize + pooling ----
  k_pool_partial<<<dim3(8, RCH), dim3(64, 4), 0, stream>>>(mu_out, lv_out, eps, beta, pmax, psum);
  k_pool_combine<<<1, 512, 0, stream>>>(pmax, psum, out1, out2);

  // ---- decoder ----
  k_decoder<<<1, 1024, 0, stream>>>(out1, out2, yt, Wd1, bd1, Wd2, bd2, out_f);
}

// Round 5
// 732.367 us; speedup vs baseline: 4.3587x; 1.3036x over previous
//
#include <hip/hip_runtime.h>

#define NN 20000
#define EE 320000
#define RCH 40
#define RPC 500
#define MPAD 20096  // NN padded to multiple of 128
#define DKB 128     // decoder partial blocks
#define DCH 9       // ceil(1025/128)

typedef unsigned short u16;
typedef unsigned int u32;
typedef __attribute__((ext_vector_type(8))) short short8;
typedef __attribute__((ext_vector_type(4))) float f32x4;

// ---------------- bf16 helpers ----------------
__device__ inline float bf16lo(u32 u) { return __uint_as_float(u << 16); }
__device__ inline float bf16hi(u32 u) { return __uint_as_float(u & 0xffff0000u); }
__device__ inline u16 f2b(float f) {
  u32 u = __float_as_uint(f);
  u += 0x7fffu + ((u >> 16) & 1u);
  return (u16)(u >> 16);
}
__device__ inline u32 pack2(float a, float b) {
  return (u32)f2b(a) | ((u32)f2b(b) << 16);
}

__device__ inline void gload16(const void* g, void* l) {
  __builtin_amdgcn_global_load_lds(
      (const __attribute__((address_space(1))) void*)g,
      (__attribute__((address_space(3))) void*)l, 16, 0, 0);
}

// ---------------- zero-init (int) ----------------
__global__ void k_zeroi(int* __restrict__ p, int n) {
  int i = blockIdx.x * blockDim.x + threadIdx.x;
  if (i < n) p[i] = 0;
}

// ---------------- fp32 -> bf16 cast (pairs) ----------------
__global__ void k_f2b2(const float* __restrict__ in, u16* __restrict__ out, int npairs) {
  for (int i = blockIdx.x * blockDim.x + threadIdx.x; i < npairs; i += gridDim.x * blockDim.x) {
    float2 v = *(const float2*)(in + 2 * i);
    ((u32*)out)[i] = pack2(v.x, v.y);
  }
}

// ---------------- weight transpose + cast: W[K x N] fp32 -> WT[N x K] bf16 ----------------
__global__ void k_wt(const float* __restrict__ W, u16* __restrict__ WT, int K, int N) {
  int k = blockIdx.y * 256 + threadIdx.x;
  int n = blockIdx.x;
  WT[(size_t)n * K + k] = f2b(W[(size_t)k * N + n]);
}

// ---------------- CSR build: count / scan / fill ----------------
__global__ void k_count(const int* __restrict__ ei, int* __restrict__ counts) {
  int e = blockIdx.x * blockDim.x + threadIdx.x;
  if (e < EE) atomicAdd(counts + ei[EE + e], 1);
}

__global__ __launch_bounds__(256)
void k_scan(const int* __restrict__ counts, int* __restrict__ rowptr, int* __restrict__ cursor) {
  const int CHUNK = (NN + 255) / 256;
  int t = threadIdx.x;
  int lo = t * CHUNK, hi = min(lo + CHUNK, NN);
  int s = 0;
  for (int i = lo; i < hi; ++i) s += counts[i];
  __shared__ int tsum[256];
  tsum[t] = s;
  __syncthreads();
  if (t == 0) {
    int run = 0;
    for (int i = 0; i < 256; ++i) { int v = tsum[i]; tsum[i] = run; run += v; }
  }
  __syncthreads();
  int run = tsum[t];
  for (int i = lo; i < hi; ++i) {
    rowptr[i] = run;
    cursor[i] = run;
    run += counts[i];
  }
  if (t == 255) rowptr[NN] = EE;
}

__global__ void k_fill(const int* __restrict__ ei, const float* __restrict__ ew,
                       int* __restrict__ cursor, int* __restrict__ colsrc,
                       float* __restrict__ ecw) {
  int e = blockIdx.x * blockDim.x + threadIdx.x;
  if (e < EE) {
    int d = ei[EE + e];
    int pos = atomicAdd(cursor + d, 1);
    colsrc[pos] = ei[e];
    ecw[pos] = ew[e];
  }
}

__global__ void k_degcsr(const int* __restrict__ rowptr, const float* __restrict__ ecw,
                         float* __restrict__ dinv, float* __restrict__ dinv2) {
  int i = blockIdx.x * blockDim.x + threadIdx.x;
  if (i < NN) {
    float s = 0.f;
    for (int e = rowptr[i]; e < rowptr[i + 1]; ++e) s += ecw[e];
    float d = s + 1.0f;
    dinv[i] = rsqrtf(d);
    dinv2[i] = 1.0f / d;
  }
}

// ---------------- bf16 MFMA GEMM: C[M,N] = A[M,K] @ BT[N,K]^T (+bias) ----------------
template <bool STORE_BF16, bool HAS_BIAS>
__global__ __launch_bounds__(256)
void k_mfma(const u16* __restrict__ A, const u16* __restrict__ BT,
            const float* __restrict__ bias, void* __restrict__ C,
            int M, int K, int N) {
  __shared__ u16 Asm[128 * 32];
  __shared__ u16 Bsm[128 * 32];
  const int tid = threadIdx.x;
  const int m0 = blockIdx.x * 128;
  const int n0 = blockIdx.y * 128;
  const int lane = tid & 63;
  const int wave = tid >> 6;
  const int wm = (wave >> 1) * 64;
  const int wn = (wave & 1) * 64;
  const int qm = lane & 15;
  const int quad = lane >> 4;

  f32x4 acc[4][4];
#pragma unroll
  for (int i = 0; i < 4; ++i)
#pragma unroll
    for (int j = 0; j < 4; ++j) acc[i][j] = (f32x4){0.f, 0.f, 0.f, 0.f};

  for (int k0 = 0; k0 < K; k0 += 32) {
#pragma unroll
    for (int h = 0; h < 2; ++h) {
      int c = h * 256 + tid;
      int row = c >> 2, kc = c & 3;
      gload16(A + (size_t)(m0 + row) * K + k0 + kc * 8, Asm + c * 8);
      gload16(BT + (size_t)(n0 + row) * K + k0 + kc * 8, Bsm + c * 8);
    }
    __syncthreads();
    short8 af[4], bfr[4];
#pragma unroll
    for (int i = 0; i < 4; ++i)
      af[i] = *(const short8*)(Asm + (wm + i * 16 + qm) * 32 + quad * 8);
#pragma unroll
    for (int j = 0; j < 4; ++j)
      bfr[j] = *(const short8*)(Bsm + (wn + j * 16 + qm) * 32 + quad * 8);
#pragma unroll
    for (int i = 0; i < 4; ++i)
#pragma unroll
      for (int j = 0; j < 4; ++j)
        acc[i][j] = __builtin_amdgcn_mfma_f32_16x16x32_bf16(af[i], bfr[j], acc[i][j], 0, 0, 0);
    __syncthreads();
  }

#pragma unroll
  for (int i = 0; i < 4; ++i) {
#pragma unroll
    for (int r = 0; r < 4; ++r) {
      int row = m0 + wm + i * 16 + quad * 4 + r;
      if (row >= M) continue;
#pragma unroll
      for (int j = 0; j < 4; ++j) {
        int col = n0 + wn + j * 16 + qm;
        float v = acc[i][j][r];
        if (HAS_BIAS) v += bias[col];
        if (STORE_BF16) ((u16*)C)[(size_t)row * N + col] = f2b(v);
        else ((float*)C)[(size_t)row * N + col] = v;
      }
    }
  }
}

// ---------------- fused CSR gather (bf16 in/out), O = 2*NT ----------------
template <int NT, bool PRE>
__global__ __launch_bounds__(NT)
void k_gather(const int* __restrict__ rowptr, const int* __restrict__ colsrc,
              const float* __restrict__ ecw, const float* __restrict__ dinv,
              const float* __restrict__ dinv2, const u16* __restrict__ xw,
              const float* __restrict__ bias, u16* __restrict__ h) {
  const int O = 2 * NT;
  const int row = blockIdx.x;
  const int tid = threadIdx.x;
  const float dv = dinv[row], dv2 = dinv2[row];
  u32 u = ((const u32*)(xw + (size_t)row * O))[tid];
  float a0 = dv2 * bf16lo(u);
  float a1 = dv2 * bf16hi(u);
  if (!PRE) { a0 += bias[2 * tid]; a1 += bias[2 * tid + 1]; }

  __shared__ int s_src[NT];
  __shared__ float s_w[NT];
  const int e0 = rowptr[row], e1 = rowptr[row + 1];
  for (int base = e0; base < e1; base += NT) {
    int cnt = min(NT, e1 - base);
    __syncthreads();
    if (tid < cnt) {
      int s = colsrc[base + tid];
      s_src[tid] = s;
      s_w[tid] = dinv[s] * ecw[base + tid] * dv;
    }
    __syncthreads();
    for (int e = 0; e < cnt; ++e) {
      float w = s_w[e];
      u32 v = ((const u32*)(xw + (size_t)s_src[e] * O))[tid];
      a0 += w * bf16lo(v);
      a1 += w * bf16hi(v);
    }
  }

  if (PRE) {
    ((u32*)h)[(size_t)row * NT + tid] = pack2(a0, a1);
    return;
  }
  float ss = a0 * a0 + a1 * a1;
#pragma unroll
  for (int off = 32; off > 0; off >>= 1) ss += __shfl_down(ss, off, 64);
  __shared__ float red[NT / 64];
  __shared__ float s_scale;
  if ((tid & 63) == 0) red[tid >> 6] = ss;
  __syncthreads();
  if (tid == 0) {
    float t = 0.f;
#pragma unroll
    for (int i = 0; i < NT / 64; ++i) t += red[i];
    s_scale = 1.0f / fmaxf(sqrtf(t), 1e-12f);
  }
  __syncthreads();
  float sc = s_scale;
  ((u32*)h)[(size_t)row * NT + tid] = pack2(fmaxf(a0 * sc, 0.f), fmaxf(a1 * sc, 0.f));
}

// ---------------- rowwise l2norm + relu, bf16 in/out, O=1024 ----------------
__global__ __launch_bounds__(256)
void k_l2relu(const u16* __restrict__ t, u16* __restrict__ h) {
  const int row = blockIdx.x;
  const int tid = threadIdx.x;
  const u32* tr = (const u32*)(t + (size_t)row * 1024);
  u32 u0 = tr[tid], u1 = tr[256 + tid];
  float a0 = bf16lo(u0), a1 = bf16hi(u0), a2 = bf16lo(u1), a3 = bf16hi(u1);
  float ss = a0 * a0 + a1 * a1 + a2 * a2 + a3 * a3;
#pragma unroll
  for (int off = 32; off > 0; off >>= 1) ss += __shfl_down(ss, off, 64);
  __shared__ float red[4];
  __shared__ float s_scale;
  if ((tid & 63) == 0) red[tid >> 6] = ss;
  __syncthreads();
  if (tid == 0) {
    float s = red[0] + red[1] + red[2] + red[3];
    s_scale = 1.0f / fmaxf(sqrtf(s), 1e-12f);
  }
  __syncthreads();
  float sc = s_scale;
  u32* hr = (u32*)(h + (size_t)row * 1024);
  hr[tid]       = pack2(fmaxf(a0 * sc, 0.f), fmaxf(a1 * sc, 0.f));
  hr[256 + tid] = pack2(fmaxf(a2 * sc, 0.f), fmaxf(a3 * sc, 0.f));
}

// ---------------- reparameterize + global max/mean pooling ----------------
__global__ void k_pool_partial(const float* __restrict__ mu, const float* __restrict__ lv,
                               const float* __restrict__ eps, const float* __restrict__ beta_p,
                               float* __restrict__ pmax, float* __restrict__ psum) {
  int tx = threadIdx.x, ty = threadIdx.y;
  int col = blockIdx.x * 64 + tx;
  int by = blockIdx.y;
  float beta = beta_p[0];
  float m = -3.4e38f, s = 0.f;
  for (int i = by * RPC + ty; i < (by + 1) * RPC; i += 4) {
    size_t idx = (size_t)i * 512 + col;
    float z = mu[idx] + 0.01f * eps[idx] * expf(0.5f * beta * lv[idx]);
    m = fmaxf(m, z);
    s += z;
  }
  __shared__ float sm[4][64], su[4][64];
  sm[ty][tx] = m; su[ty][tx] = s;
  __syncthreads();
  if (ty == 0) {
    m = fmaxf(fmaxf(sm[0][tx], sm[1][tx]), fmaxf(sm[2][tx], sm[3][tx]));
    s = su[0][tx] + su[1][tx] + su[2][tx] + su[3][tx];
    pmax[(size_t)by * 512 + col] = m;
    psum[(size_t)by * 512 + col] = s;
  }
}

// writes rz[1025] = [max-pool | mean-pool | y_target]
__global__ void k_pool_combine(const float* __restrict__ pmax, const float* __restrict__ psum,
                               const float* __restrict__ yt, float* __restrict__ rz) {
  int col = threadIdx.x;
  float m = -3.4e38f, s = 0.f;
  for (int c = 0; c < RCH; ++c) {
    m = fmaxf(m, pmax[(size_t)c * 512 + col]);
    s += psum[(size_t)c * 512 + col];
  }
  rz[col] = m;
  rz[512 + col] = s / (float)NN;
  if (col == 0) rz[1024] = yt[0];
}

// ---------------- parallel decoder: partial over k-chunks + combine ----------------
// partial[b][n] = sum_{k in chunk b} v[k] * W[k*Ndim + n]
__global__ __launch_bounds__(256)
void k_dec_partial(const float* __restrict__ v, const float* __restrict__ W,
                   float* __restrict__ partial, int Kdim, int Ndim) {
  int b = blockIdx.x;
  int lo = b * DCH;
  float rv[DCH];
#pragma unroll
  for (int j = 0; j < DCH; ++j) rv[j] = (lo + j < Kdim) ? v[lo + j] : 0.f;
  for (int n = threadIdx.x; n < Ndim; n += 256) {
    float s = 0.f;
#pragma unroll
    for (int j = 0; j < DCH; ++j)
      if (lo + j < Kdim) s += rv[j] * W[(size_t)(lo + j) * Ndim + n];
    partial[(size_t)b * Ndim + n] = s;
  }
}

// ACT: 0 = relu, 1 = sigmoid
template <int ACT>
__global__ __launch_bounds__(256)
void k_dec_combine(const float* __restrict__ partial, const float* __restrict__ bias,
                   float* __restrict__ out, int Ndim) {
  int n = blockIdx.x * 256 + threadIdx.x;
  if (n >= Ndim) return;
  float s = bias[n];
  for (int b = 0; b < DKB; ++b) s += partial[(size_t)b * Ndim + n];
  out[n] = (ACT == 0) ? fmaxf(s, 0.f) : 1.0f / (1.0f + expf(-s));
}

extern "C" void kernel_launch(void* const* d_in, const int* in_sizes, int n_in,
                              void* d_out, int out_size, void* d_ws, size_t ws_size,
                              hipStream_t stream) {
  const float* x    = (const float*)d_in[0];
  const int*   ei   = (const int*)d_in[1];
  const float* ew   = (const float*)d_in[2];
  const float* beta = (const float*)d_in[3];
  const float* yt   = (const float*)d_in[4];
  const float* eps  = (const float*)d_in[5];
  const float* W1   = (const float*)d_in[6];  const float* b1  = (const float*)d_in[7];
  const float* W2   = (const float*)d_in[8];  const float* b2  = (const float*)d_in[9];
  const float* W3   = (const float*)d_in[10]; const float* b3  = (const float*)d_in[11];
  const float* Wmu  = (const float*)d_in[12]; const float* bmu = (const float*)d_in[13];
  const float* Wlv  = (const float*)d_in[14]; const float* blv = (const float*)d_in[15];
  const float* Wd1  = (const float*)d_in[16]; const float* bd1 = (const float*)d_in[17];
  const float* Wd2  = (const float*)d_in[18]; const float* bd2 = (const float*)d_in[19];

  char* wsb = (char*)d_ws;
  size_t off = 0;
  auto alloc_f = [&](size_t n) { float* p = (float*)(wsb + off); off += n * sizeof(float); return p; };
  auto alloc_i = [&](size_t n) { int* p = (int*)(wsb + off); off += n * sizeof(int); return p; };
  auto alloc_h = [&](size_t n) { u16* p = (u16*)(wsb + off); off += ((n * 2 + 3) & ~(size_t)3); return p; };

  int* counts  = alloc_i(NN);
  int* rowptr  = alloc_i(NN + 1);
  int* cursor  = alloc_i(NN);
  int* colsrc  = alloc_i(EE);
  float* ecw   = alloc_f(EE);
  float* dinv  = alloc_f(NN);
  float* din2  = alloc_f(NN);
  float* pmax  = alloc_f(RCH * 512);
  float* psum  = alloc_f(RCH * 512);
  float* rz    = alloc_f(1028);
  float* hdec  = alloc_f(1028);
  float* part1 = alloc_f((size_t)DKB * 1025);
  float* part2 = alloc_f((size_t)DKB * 1024);
  u16* W1T  = alloc_h(1024 * 512);
  u16* W2T  = alloc_h(512 * 1024);
  u16* W3T  = alloc_h(256 * 512);
  u16* WmuT = alloc_h(512 * 256);
  u16* WlvT = alloc_h(512 * 256);
  u16* xb   = alloc_h((size_t)MPAD * 512);   // x bf16; later reused as h3 (256)
  u16* aggx = alloc_h((size_t)MPAD * 512);   // pre-aggregated x
  u16* bufT = alloc_h((size_t)MPAD * 1024);  // t1; later z2 (512)
  u16* bufH = alloc_h((size_t)MPAD * 1024);  // h1; later z3 (256)
  u16* h2   = alloc_h((size_t)MPAD * 512);
  u16* h3   = xb;
  u16* z2   = bufT;
  u16* z3   = bufH;

  float* out_f  = (float*)d_out;
  float* mu_out = out_f + 1024;
  float* lv_out = out_f + 1024 + (size_t)NN * 512;

  const int MT = (NN + 127) / 128;  // 157

  // ---- casts / transposes ----
  k_f2b2<<<4096, 256, 0, stream>>>(x, xb, NN * 512 / 2);
  k_wt<<<dim3(1024, 2), 256, 0, stream>>>(W1, W1T, 512, 1024);
  k_wt<<<dim3(512, 4), 256, 0, stream>>>(W2, W2T, 1024, 512);
  k_wt<<<dim3(256, 2), 256, 0, stream>>>(W3, W3T, 512, 256);
  k_wt<<<dim3(512, 1), 256, 0, stream>>>(Wmu, WmuT, 256, 512);
  k_wt<<<dim3(512, 1), 256, 0, stream>>>(Wlv, WlvT, 256, 512);

  // ---- CSR build + degree norms ----
  k_zeroi<<<(NN + 255) / 256, 256, 0, stream>>>(counts, NN);
  k_count<<<(EE + 255) / 256, 256, 0, stream>>>(ei, counts);
  k_scan<<<1, 256, 0, stream>>>(counts, rowptr, cursor);
  k_fill<<<(EE + 255) / 256, 256, 0, stream>>>(ei, ew, cursor, colsrc, ecw);
  k_degcsr<<<(NN + 255) / 256, 256, 0, stream>>>(rowptr, ecw, dinv, din2);

  // ---- layer 1: aggregate x first (linearity), then GEMM+bias, then l2relu ----
  k_gather<256, true><<<NN, 256, 0, stream>>>(rowptr, colsrc, ecw, dinv, din2, xb, nullptr, aggx);
  k_mfma<true, true><<<dim3(MT, 8), 256, 0, stream>>>(aggx, W1T, b1, bufT, NN, 512, 1024);
  k_l2relu<<<NN, 256, 0, stream>>>(bufT, bufH);

  // ---- layer 2: GEMM then fused gather+bias+l2relu ----
  k_mfma<true, false><<<dim3(MT, 4), 256, 0, stream>>>(bufH, W2T, nullptr, z2, NN, 1024, 512);
  k_gather<256, false><<<NN, 256, 0, stream>>>(rowptr, colsrc, ecw, dinv, din2, z2, b2, h2);

  // ---- layer 3 ----
  k_mfma<true, false><<<dim3(MT, 2), 256, 0, stream>>>(h2, W3T, nullptr, z3, NN, 512, 256);
  k_gather<128, false><<<NN, 128, 0, stream>>>(rowptr, colsrc, ecw, dinv, din2, z3, b3, h3);

  // ---- VAE heads: fp32 out with bias ----
  k_mfma<false, true><<<dim3(MT, 4), 256, 0, stream>>>(h3, WmuT, bmu, mu_out, NN, 256, 512);
  k_mfma<false, true><<<dim3(MT, 4), 256, 0, stream>>>(h3, WlvT, blv, lv_out, NN, 256, 512);

  // ---- reparameterize + pooling ----
  k_pool_partial<<<dim3(8, RCH), dim3(64, 4), 0, stream>>>(mu_out, lv_out, eps, beta, pmax, psum);
  k_pool_combine<<<1, 512, 0, stream>>>(pmax, psum, yt, rz);

  // ---- parallel decoder ----
  k_dec_partial<<<DKB, 256, 0, stream>>>(rz, Wd1, part1, 1025, 1025);
  k_dec_combine<0><<<5, 256, 0, stream>>>(part1, bd1, hdec, 1025);
  k_dec_partial<<<DKB, 256, 0, stream>>>(hdec, Wd2, part2, 1025, 1024);
  k_dec_combine<1><<<4, 256, 0, stream>>>(part2, bd2, out_f, 1024);
}

// Round 6
// 707.881 us; speedup vs baseline: 4.5095x; 1.0346x over previous
//
#include <hip/hip_runtime.h>

#define NN 20000
#define EE 320000
#define MPAD 20096   // NN padded to multiple of 128
#define MTILES 157   // ceil(NN/128)
#define DKB 128      // decoder partial blocks
#define DCH 9        // ceil(1025/128)

typedef unsigned short u16;
typedef unsigned int u32;
typedef __attribute__((ext_vector_type(8))) short short8;
typedef __attribute__((ext_vector_type(4))) float f32x4;

// ---------------- bf16 helpers ----------------
__device__ inline float bf16lo(u32 u) { return __uint_as_float(u << 16); }
__device__ inline float bf16hi(u32 u) { return __uint_as_float(u & 0xffff0000u); }
__device__ inline u16 f2b(float f) {
  u32 u = __float_as_uint(f);
  u += 0x7fffu + ((u >> 16) & 1u);
  return (u16)(u >> 16);
}
__device__ inline u32 pack2(float a, float b) {
  return (u32)f2b(a) | ((u32)f2b(b) << 16);
}

__device__ inline void gload16(const void* g, void* l) {
  __builtin_amdgcn_global_load_lds(
      (const __attribute__((address_space(1))) void*)g,
      (__attribute__((address_space(3))) void*)l, 16, 0, 0);
}

// ---------------- zero-init (int) ----------------
__global__ void k_zeroi(int* __restrict__ p, int n) {
  int i = blockIdx.x * blockDim.x + threadIdx.x;
  if (i < n) p[i] = 0;
}

// ---------------- fp32 -> bf16 cast (pairs) ----------------
__global__ void k_f2b2(const float* __restrict__ in, u16* __restrict__ out, int npairs) {
  for (int i = blockIdx.x * blockDim.x + threadIdx.x; i < npairs; i += gridDim.x * blockDim.x) {
    float2 v = *(const float2*)(in + 2 * i);
    ((u32*)out)[i] = pack2(v.x, v.y);
  }
}

// ---------------- weight transpose + cast: W[K x N] fp32 -> WT[N x K] bf16 ----------------
__global__ void k_wt(const float* __restrict__ W, u16* __restrict__ WT, int K, int N) {
  int k = blockIdx.y * 256 + threadIdx.x;
  int n = blockIdx.x;
  WT[(size_t)n * K + k] = f2b(W[(size_t)k * N + n]);
}

// ---------------- CSR build: count / scan / fill ----------------
__global__ void k_count(const int* __restrict__ ei, int* __restrict__ counts) {
  int e = blockIdx.x * blockDim.x + threadIdx.x;
  if (e < EE) atomicAdd(counts + ei[EE + e], 1);
}

__global__ __launch_bounds__(256)
void k_scan(const int* __restrict__ counts, int* __restrict__ rowptr, int* __restrict__ cursor) {
  const int CHUNK = (NN + 255) / 256;
  int t = threadIdx.x;
  int lo = t * CHUNK, hi = min(lo + CHUNK, NN);
  int s = 0;
  for (int i = lo; i < hi; ++i) s += counts[i];
  __shared__ int tsum[256];
  tsum[t] = s;
  __syncthreads();
  if (t == 0) {
    int run = 0;
    for (int i = 0; i < 256; ++i) { int v = tsum[i]; tsum[i] = run; run += v; }
  }
  __syncthreads();
  int run = tsum[t];
  for (int i = lo; i < hi; ++i) {
    rowptr[i] = run;
    cursor[i] = run;
    run += counts[i];
  }
  if (t == 255) rowptr[NN] = EE;
}

__global__ void k_fill(const int* __restrict__ ei, const float* __restrict__ ew,
                       int* __restrict__ cursor, int* __restrict__ colsrc,
                       float* __restrict__ ecw) {
  int e = blockIdx.x * blockDim.x + threadIdx.x;
  if (e < EE) {
    int d = ei[EE + e];
    int pos = atomicAdd(cursor + d, 1);
    colsrc[pos] = ei[e];
    ecw[pos] = ew[e];
  }
}

__global__ void k_degcsr(const int* __restrict__ rowptr, const float* __restrict__ ecw,
                         float* __restrict__ dinv, float* __restrict__ dinv2) {
  int i = blockIdx.x * blockDim.x + threadIdx.x;
  if (i < NN) {
    float s = 0.f;
    for (int e = rowptr[i]; e < rowptr[i + 1]; ++e) s += ecw[e];
    float d = s + 1.0f;
    dinv[i] = rsqrtf(d);
    dinv2[i] = 1.0f / d;
  }
}

// ---------------- bf16 MFMA GEMM: C[M,N] = A[M,K] @ BT[N,K]^T (+bias) ----------------
template <bool STORE_BF16, bool HAS_BIAS>
__global__ __launch_bounds__(256)
void k_mfma(const u16* __restrict__ A, const u16* __restrict__ BT,
            const float* __restrict__ bias, void* __restrict__ C,
            int M, int K, int N) {
  __shared__ u16 Asm[128 * 32];
  __shared__ u16 Bsm[128 * 32];
  const int tid = threadIdx.x;
  const int m0 = blockIdx.x * 128;
  const int n0 = blockIdx.y * 128;
  const int lane = tid & 63;
  const int wave = tid >> 6;
  const int wm = (wave >> 1) * 64;
  const int wn = (wave & 1) * 64;
  const int qm = lane & 15;
  const int quad = lane >> 4;

  f32x4 acc[4][4];
#pragma unroll
  for (int i = 0; i < 4; ++i)
#pragma unroll
    for (int j = 0; j < 4; ++j) acc[i][j] = (f32x4){0.f, 0.f, 0.f, 0.f};

  for (int k0 = 0; k0 < K; k0 += 32) {
#pragma unroll
    for (int h = 0; h < 2; ++h) {
      int c = h * 256 + tid;
      int row = c >> 2, kc = c & 3;
      gload16(A + (size_t)(m0 + row) * K + k0 + kc * 8, Asm + c * 8);
      gload16(BT + (size_t)(n0 + row) * K + k0 + kc * 8, Bsm + c * 8);
    }
    __syncthreads();
    short8 af[4], bfr[4];
#pragma unroll
    for (int i = 0; i < 4; ++i)
      af[i] = *(const short8*)(Asm + (wm + i * 16 + qm) * 32 + quad * 8);
#pragma unroll
    for (int j = 0; j < 4; ++j)
      bfr[j] = *(const short8*)(Bsm + (wn + j * 16 + qm) * 32 + quad * 8);
#pragma unroll
    for (int i = 0; i < 4; ++i)
#pragma unroll
      for (int j = 0; j < 4; ++j)
        acc[i][j] = __builtin_amdgcn_mfma_f32_16x16x32_bf16(af[i], bfr[j], acc[i][j], 0, 0, 0);
    __syncthreads();
  }

#pragma unroll
  for (int i = 0; i < 4; ++i) {
#pragma unroll
    for (int r = 0; r < 4; ++r) {
      int row = m0 + wm + i * 16 + quad * 4 + r;
      if (row >= M) continue;
#pragma unroll
      for (int j = 0; j < 4; ++j) {
        int col = n0 + wn + j * 16 + qm;
        float v = acc[i][j][r];
        if (HAS_BIAS) v += bias[col];
        if (STORE_BF16) ((u16*)C)[(size_t)row * N + col] = f2b(v);
        else ((float*)C)[(size_t)row * N + col] = v;
      }
    }
  }
}

// ---------------- dual-head MFMA: mu & logvar in one pass + fused z-pooling ----------------
// A[M,256] @ {WmuT,WlvT}[512,256]^T; epilogue: store mu/lv fp32, compute
// z = mu + 0.01*eps*exp(0.5*beta*lv), per-(m-tile,col) max/sum partials.
__global__ __launch_bounds__(256)
void k_heads(const u16* __restrict__ A, const u16* __restrict__ BmuT,
             const u16* __restrict__ BlvT, const float* __restrict__ bmu,
             const float* __restrict__ blv, const float* __restrict__ eps,
             const float* __restrict__ beta_p, float* __restrict__ mu_out,
             float* __restrict__ lv_out, float* __restrict__ pmax,
             float* __restrict__ psum) {
  const int K = 256, N = 512;
  __shared__ u16 Asm[128 * 32];
  __shared__ u16 Bmu[128 * 32];
  __shared__ u16 Blv[128 * 32];
  __shared__ float smax[256], ssum[256];
  const int tid = threadIdx.x;
  const int m0 = blockIdx.x * 128;
  const int n0 = blockIdx.y * 128;
  const int lane = tid & 63;
  const int wave = tid >> 6;
  const int wm = (wave >> 1) * 64;
  const int wn = (wave & 1) * 64;
  const int qm = lane & 15;
  const int quad = lane >> 4;

  f32x4 am[4][4], al[4][4];
#pragma unroll
  for (int i = 0; i < 4; ++i)
#pragma unroll
    for (int j = 0; j < 4; ++j) {
      am[i][j] = (f32x4){0.f, 0.f, 0.f, 0.f};
      al[i][j] = (f32x4){0.f, 0.f, 0.f, 0.f};
    }

  for (int k0 = 0; k0 < K; k0 += 32) {
#pragma unroll
    for (int h = 0; h < 2; ++h) {
      int c = h * 256 + tid;
      int row = c >> 2, kc = c & 3;
      gload16(A + (size_t)(m0 + row) * K + k0 + kc * 8, Asm + c * 8);
      gload16(BmuT + (size_t)(n0 + row) * K + k0 + kc * 8, Bmu + c * 8);
      gload16(BlvT + (size_t)(n0 + row) * K + k0 + kc * 8, Blv + c * 8);
    }
    __syncthreads();
    short8 af[4], bm[4], bl[4];
#pragma unroll
    for (int i = 0; i < 4; ++i)
      af[i] = *(const short8*)(Asm + (wm + i * 16 + qm) * 32 + quad * 8);
#pragma unroll
    for (int j = 0; j < 4; ++j) {
      bm[j] = *(const short8*)(Bmu + (wn + j * 16 + qm) * 32 + quad * 8);
      bl[j] = *(const short8*)(Blv + (wn + j * 16 + qm) * 32 + quad * 8);
    }
#pragma unroll
    for (int i = 0; i < 4; ++i)
#pragma unroll
      for (int j = 0; j < 4; ++j) {
        am[i][j] = __builtin_amdgcn_mfma_f32_16x16x32_bf16(af[i], bm[j], am[i][j], 0, 0, 0);
        al[i][j] = __builtin_amdgcn_mfma_f32_16x16x32_bf16(af[i], bl[j], al[i][j], 0, 0, 0);
      }
    __syncthreads();
  }

  const float beta = beta_p[0];
  float biasm[4], biasl[4];
#pragma unroll
  for (int j = 0; j < 4; ++j) {
    int col = n0 + wn + j * 16 + qm;
    biasm[j] = bmu[col];
    biasl[j] = blv[col];
  }
  float zmax[4] = {-3.4e38f, -3.4e38f, -3.4e38f, -3.4e38f};
  float zsum[4] = {0.f, 0.f, 0.f, 0.f};
#pragma unroll
  for (int i = 0; i < 4; ++i) {
#pragma unroll
    for (int r = 0; r < 4; ++r) {
      int row = m0 + wm + i * 16 + quad * 4 + r;
      if (row >= NN) continue;
#pragma unroll
      for (int j = 0; j < 4; ++j) {
        int col = n0 + wn + j * 16 + qm;
        float vm = am[i][j][r] + biasm[j];
        float vl = al[i][j][r] + biasl[j];
        size_t idx = (size_t)row * N + col;
        mu_out[idx] = vm;
        lv_out[idx] = vl;
        float z = vm + 0.01f * eps[idx] * expf(0.5f * beta * vl);
        zmax[j] = fmaxf(zmax[j], z);
        zsum[j] += z;
      }
    }
  }
  // reduce across the 4 quads (lanes qm, qm+16, qm+32, qm+48)
#pragma unroll
  for (int j = 0; j < 4; ++j) {
#pragma unroll
    for (int off = 16; off <= 32; off <<= 1) {
      zmax[j] = fmaxf(zmax[j], __shfl_xor(zmax[j], off, 64));
      zsum[j] += __shfl_xor(zsum[j], off, 64);
    }
  }
  if (quad == 0) {
#pragma unroll
    for (int j = 0; j < 4; ++j) {
      smax[wave * 64 + j * 16 + qm] = zmax[j];
      ssum[wave * 64 + j * 16 + qm] = zsum[j];
    }
  }
  __syncthreads();
  // combine the two wm-halves: cols 0..63 from waves {0,2}, 64..127 from {1,3}
  if (tid < 128) {
    int cn = tid;
    int w0 = (cn < 64) ? 0 : 1;
    int c = cn & 63;
    float m = fmaxf(smax[w0 * 64 + c], smax[(w0 + 2) * 64 + c]);
    float s = ssum[w0 * 64 + c] + ssum[(w0 + 2) * 64 + c];
    pmax[(size_t)blockIdx.x * N + n0 + cn] = m;
    psum[(size_t)blockIdx.x * N + n0 + cn] = s;
  }
}

// rz[1025] = [max-pool | mean-pool | y_target], reducing MTILES partials
__global__ void k_zred(const float* __restrict__ pmax, const float* __restrict__ psum,
                       const float* __restrict__ yt, float* __restrict__ rz) {
  int col = threadIdx.x;  // 512 threads
  float m = -3.4e38f, s = 0.f;
  for (int c = 0; c < MTILES; ++c) {
    m = fmaxf(m, pmax[(size_t)c * 512 + col]);
    s += psum[(size_t)c * 512 + col];
  }
  rz[col] = m;
  rz[512 + col] = s / (float)NN;
  if (col == 0) rz[1024] = yt[0];
}

// ---------------- fused CSR gather (bf16 in/out), O = 2*NT ----------------
template <int NT, bool PRE>
__global__ __launch_bounds__(NT)
void k_gather(const int* __restrict__ rowptr, const int* __restrict__ colsrc,
              const float* __restrict__ ecw, const float* __restrict__ dinv,
              const float* __restrict__ dinv2, const u16* __restrict__ xw,
              const float* __restrict__ bias, u16* __restrict__ h) {
  const int O = 2 * NT;
  const int row = blockIdx.x;
  const int tid = threadIdx.x;
  const float dv = dinv[row], dv2 = dinv2[row];
  u32 u = ((const u32*)(xw + (size_t)row * O))[tid];
  float a0 = dv2 * bf16lo(u);
  float a1 = dv2 * bf16hi(u);
  if (!PRE) { a0 += bias[2 * tid]; a1 += bias[2 * tid + 1]; }

  __shared__ int s_src[NT];
  __shared__ float s_w[NT];
  const int e0 = rowptr[row], e1 = rowptr[row + 1];
  for (int base = e0; base < e1; base += NT) {
    int cnt = min(NT, e1 - base);
    __syncthreads();
    if (tid < cnt) {
      int s = colsrc[base + tid];
      s_src[tid] = s;
      s_w[tid] = dinv[s] * ecw[base + tid] * dv;
    }
    __syncthreads();
    for (int e = 0; e < cnt; ++e) {
      float w = s_w[e];
      u32 v = ((const u32*)(xw + (size_t)s_src[e] * O))[tid];
      a0 += w * bf16lo(v);
      a1 += w * bf16hi(v);
    }
  }

  if (PRE) {
    ((u32*)h)[(size_t)row * NT + tid] = pack2(a0, a1);
    return;
  }
  float ss = a0 * a0 + a1 * a1;
#pragma unroll
  for (int off = 32; off > 0; off >>= 1) ss += __shfl_down(ss, off, 64);
  __shared__ float red[NT / 64];
  __shared__ float s_scale;
  if ((tid & 63) == 0) red[tid >> 6] = ss;
  __syncthreads();
  if (tid == 0) {
    float t = 0.f;
#pragma unroll
    for (int i = 0; i < NT / 64; ++i) t += red[i];
    s_scale = 1.0f / fmaxf(sqrtf(t), 1e-12f);
  }
  __syncthreads();
  float sc = s_scale;
  ((u32*)h)[(size_t)row * NT + tid] = pack2(fmaxf(a0 * sc, 0.f), fmaxf(a1 * sc, 0.f));
}

// ---------------- rowwise l2norm + relu, bf16 in/out, O=1024 ----------------
__global__ __launch_bounds__(256)
void k_l2relu(const u16* __restrict__ t, u16* __restrict__ h) {
  const int row = blockIdx.x;
  const int tid = threadIdx.x;
  const u32* tr = (const u32*)(t + (size_t)row * 1024);
  u32 u0 = tr[tid], u1 = tr[256 + tid];
  float a0 = bf16lo(u0), a1 = bf16hi(u0), a2 = bf16lo(u1), a3 = bf16hi(u1);
  float ss = a0 * a0 + a1 * a1 + a2 * a2 + a3 * a3;
#pragma unroll
  for (int off = 32; off > 0; off >>= 1) ss += __shfl_down(ss, off, 64);
  __shared__ float red[4];
  __shared__ float s_scale;
  if ((tid & 63) == 0) red[tid >> 6] = ss;
  __syncthreads();
  if (tid == 0) {
    float s = red[0] + red[1] + red[2] + red[3];
    s_scale = 1.0f / fmaxf(sqrtf(s), 1e-12f);
  }
  __syncthreads();
  float sc = s_scale;
  u32* hr = (u32*)(h + (size_t)row * 1024);
  hr[tid]       = pack2(fmaxf(a0 * sc, 0.f), fmaxf(a1 * sc, 0.f));
  hr[256 + tid] = pack2(fmaxf(a2 * sc, 0.f), fmaxf(a3 * sc, 0.f));
}

// ---------------- parallel decoder ----------------
__global__ __launch_bounds__(256)
void k_dec_partial(const float* __restrict__ v, const float* __restrict__ W,
                   float* __restrict__ partial, int Kdim, int Ndim) {
  int b = blockIdx.x;
  int lo = b * DCH;
  float rv[DCH];
#pragma unroll
  for (int j = 0; j < DCH; ++j) rv[j] = (lo + j < Kdim) ? v[lo + j] : 0.f;
  for (int n = threadIdx.x; n < Ndim; n += 256) {
    float s = 0.f;
#pragma unroll
    for (int j = 0; j < DCH; ++j)
      if (lo + j < Kdim) s += rv[j] * W[(size_t)(lo + j) * Ndim + n];
    partial[(size_t)b * Ndim + n] = s;
  }
}

template <int ACT>
__global__ __launch_bounds__(256)
void k_dec_combine(const float* __restrict__ partial, const float* __restrict__ bias,
                   float* __restrict__ out, int Ndim) {
  int n = blockIdx.x * 256 + threadIdx.x;
  if (n >= Ndim) return;
  float s = bias[n];
  for (int b = 0; b < DKB; ++b) s += partial[(size_t)b * Ndim + n];
  out[n] = (ACT == 0) ? fmaxf(s, 0.f) : 1.0f / (1.0f + expf(-s));
}

extern "C" void kernel_launch(void* const* d_in, const int* in_sizes, int n_in,
                              void* d_out, int out_size, void* d_ws, size_t ws_size,
                              hipStream_t stream) {
  const float* x    = (const float*)d_in[0];
  const int*   ei   = (const int*)d_in[1];
  const float* ew   = (const float*)d_in[2];
  const float* beta = (const float*)d_in[3];
  const float* yt   = (const float*)d_in[4];
  const float* eps  = (const float*)d_in[5];
  const float* W1   = (const float*)d_in[6];  const float* b1  = (const float*)d_in[7];
  const float* W2   = (const float*)d_in[8];  const float* b2  = (const float*)d_in[9];
  const float* W3   = (const float*)d_in[10]; const float* b3  = (const float*)d_in[11];
  const float* Wmu  = (const float*)d_in[12]; const float* bmu = (const float*)d_in[13];
  const float* Wlv  = (const float*)d_in[14]; const float* blv = (const float*)d_in[15];
  const float* Wd1  = (const float*)d_in[16]; const float* bd1 = (const float*)d_in[17];
  const float* Wd2  = (const float*)d_in[18]; const float* bd2 = (const float*)d_in[19];

  char* wsb = (char*)d_ws;
  size_t off = 0;
  auto alloc_f = [&](size_t n) { float* p = (float*)(wsb + off); off += n * sizeof(float); return p; };
  auto alloc_i = [&](size_t n) { int* p = (int*)(wsb + off); off += n * sizeof(int); return p; };
  auto alloc_h = [&](size_t n) { u16* p = (u16*)(wsb + off); off += ((n * 2 + 3) & ~(size_t)3); return p; };

  int* counts  = alloc_i(NN);
  int* rowptr  = alloc_i(NN + 1);
  int* cursor  = alloc_i(NN);
  int* colsrc  = alloc_i(EE);
  float* ecw   = alloc_f(EE);
  float* dinv  = alloc_f(NN);
  float* din2  = alloc_f(NN);
  float* pmax  = alloc_f((size_t)MTILES * 512);
  float* psum  = alloc_f((size_t)MTILES * 512);
  float* rz    = alloc_f(1028);
  float* hdec  = alloc_f(1028);
  float* part1 = alloc_f((size_t)DKB * 1025);
  float* part2 = alloc_f((size_t)DKB * 1024);
  u16* W1T  = alloc_h(1024 * 512);
  u16* W2T  = alloc_h(512 * 1024);
  u16* W3T  = alloc_h(256 * 512);
  u16* WmuT = alloc_h(512 * 256);
  u16* WlvT = alloc_h(512 * 256);
  u16* xb   = alloc_h((size_t)MPAD * 512);   // x bf16; later reused as h3 (256)
  u16* aggx = alloc_h((size_t)MPAD * 512);   // pre-aggregated x
  u16* bufT = alloc_h((size_t)MPAD * 1024);  // t1; later z2 (512)
  u16* bufH = alloc_h((size_t)MPAD * 1024);  // h1; later z3 (256)
  u16* h2   = alloc_h((size_t)MPAD * 512);
  u16* h3   = xb;
  u16* z2   = bufT;
  u16* z3   = bufH;

  float* out_f  = (float*)d_out;
  float* mu_out = out_f + 1024;
  float* lv_out = out_f + 1024 + (size_t)NN * 512;

  const int MT = MTILES;

  // ---- casts / transposes ----
  k_f2b2<<<4096, 256, 0, stream>>>(x, xb, NN * 512 / 2);
  k_wt<<<dim3(1024, 2), 256, 0, stream>>>(W1, W1T, 512, 1024);
  k_wt<<<dim3(512, 4), 256, 0, stream>>>(W2, W2T, 1024, 512);
  k_wt<<<dim3(256, 2), 256, 0, stream>>>(W3, W3T, 512, 256);
  k_wt<<<dim3(512, 1), 256, 0, stream>>>(Wmu, WmuT, 256, 512);
  k_wt<<<dim3(512, 1), 256, 0, stream>>>(Wlv, WlvT, 256, 512);

  // ---- CSR build + degree norms ----
  k_zeroi<<<(NN + 255) / 256, 256, 0, stream>>>(counts, NN);
  k_count<<<(EE + 255) / 256, 256, 0, stream>>>(ei, counts);
  k_scan<<<1, 256, 0, stream>>>(counts, rowptr, cursor);
  k_fill<<<(EE + 255) / 256, 256, 0, stream>>>(ei, ew, cursor, colsrc, ecw);
  k_degcsr<<<(NN + 255) / 256, 256, 0, stream>>>(rowptr, ecw, dinv, din2);

  // ---- layer 1: aggregate x first (linearity), then GEMM+bias, then l2relu ----
  k_gather<256, true><<<NN, 256, 0, stream>>>(rowptr, colsrc, ecw, dinv, din2, xb, nullptr, aggx);
  k_mfma<true, true><<<dim3(MT, 8), 256, 0, stream>>>(aggx, W1T, b1, bufT, NN, 512, 1024);
  k_l2relu<<<NN, 256, 0, stream>>>(bufT, bufH);

  // ---- layer 2: GEMM then fused gather+bias+l2relu ----
  k_mfma<true, false><<<dim3(MT, 4), 256, 0, stream>>>(bufH, W2T, nullptr, z2, NN, 1024, 512);
  k_gather<256, false><<<NN, 256, 0, stream>>>(rowptr, colsrc, ecw, dinv, din2, z2, b2, h2);

  // ---- layer 3 ----
  k_mfma<true, false><<<dim3(MT, 2), 256, 0, stream>>>(h2, W3T, nullptr, z3, NN, 512, 256);
  k_gather<128, false><<<NN, 128, 0, stream>>>(rowptr, colsrc, ecw, dinv, din2, z3, b3, h3);

  // ---- fused VAE heads + reparameterize + partial pooling ----
  k_heads<<<dim3(MT, 4), 256, 0, stream>>>(h3, WmuT, WlvT, bmu, blv, eps, beta,
                                           mu_out, lv_out, pmax, psum);
  k_zred<<<1, 512, 0, stream>>>(pmax, psum, yt, rz);

  // ---- parallel decoder ----
  k_dec_partial<<<DKB, 256, 0, stream>>>(rz, Wd1, part1, 1025, 1025);
  k_dec_combine<0><<<5, 256, 0, stream>>>(part1, bd1, hdec, 1025);
  k_dec_partial<<<DKB, 256, 0, stream>>>(hdec, Wd2, part2, 1025, 1024);
  k_dec_combine<1><<<4, 256, 0, stream>>>(part2, bd2, out_f, 1024);
}

// Round 7
// 687.214 us; speedup vs baseline: 4.6451x; 1.0301x over previous
//
#include <hip/hip_runtime.h>

#define NN 20000
#define EE 320000
#define MPAD 20096   // NN padded to multiple of 128
#define MTILES 157   // ceil(NN/128)
#define DKB 128      // decoder partial blocks
#define DCH 9        // ceil(1025/128)

typedef unsigned short u16;
typedef unsigned int u32;
typedef __attribute__((ext_vector_type(8))) short short8;
typedef __attribute__((ext_vector_type(4))) float f32x4;

// ---------------- bf16 helpers ----------------
__device__ inline float bf16lo(u32 u) { return __uint_as_float(u << 16); }
__device__ inline float bf16hi(u32 u) { return __uint_as_float(u & 0xffff0000u); }
__device__ inline u16 f2b(float f) {
  u32 u = __float_as_uint(f);
  u += 0x7fffu + ((u >> 16) & 1u);
  return (u16)(u >> 16);
}
__device__ inline u32 pack2(float a, float b) {
  return (u32)f2b(a) | ((u32)f2b(b) << 16);
}

__device__ inline void gload16(const void* g, void* l) {
  __builtin_amdgcn_global_load_lds(
      (const __attribute__((address_space(1))) void*)g,
      (__attribute__((address_space(3))) void*)l, 16, 0, 0);
}

// ---------------- zero-init (int) ----------------
__global__ void k_zeroi(int* __restrict__ p, int n) {
  int i = blockIdx.x * blockDim.x + threadIdx.x;
  if (i < n) p[i] = 0;
}

// ---------------- fp32 -> bf16 cast (pairs) ----------------
__global__ void k_f2b2(const float* __restrict__ in, u16* __restrict__ out, int npairs) {
  for (int i = blockIdx.x * blockDim.x + threadIdx.x; i < npairs; i += gridDim.x * blockDim.x) {
    float2 v = *(const float2*)(in + 2 * i);
    ((u32*)out)[i] = pack2(v.x, v.y);
  }
}

// ---------------- all weight transposes in one launch ----------------
// W[K x N] fp32 -> WT[N x K] bf16, 5 matrices by blockIdx range
__global__ void k_wt_all(const float* __restrict__ W1, const float* __restrict__ W2,
                         const float* __restrict__ W3, const float* __restrict__ Wmu,
                         const float* __restrict__ Wlv,
                         u16* __restrict__ T1, u16* __restrict__ T2,
                         u16* __restrict__ T3, u16* __restrict__ Tmu,
                         u16* __restrict__ Tlv) {
  int b = blockIdx.x;
  const float* W; u16* T; int K, N;
  if (b < 2048)      { W = W1;  T = T1;  K = 512;  N = 1024; }
  else if (b < 4096) { W = W2;  T = T2;  K = 1024; N = 512;  b -= 2048; }
  else if (b < 4608) { W = W3;  T = T3;  K = 512;  N = 256;  b -= 4096; }
  else if (b < 5120) { W = Wmu; T = Tmu; K = 256;  N = 512;  b -= 4608; }
  else               { W = Wlv; T = Tlv; K = 256;  N = 512;  b -= 5120; }
  int kb = K >> 8;
  int n = b / kb;
  int k = (b % kb) * 256 + threadIdx.x;
  T[(size_t)n * K + k] = f2b(W[(size_t)k * N + n]);
}

// ---------------- CSR build: count / scan / fill ----------------
__global__ void k_count(const int* __restrict__ ei, int* __restrict__ counts) {
  int e = blockIdx.x * blockDim.x + threadIdx.x;
  if (e < EE) atomicAdd(counts + ei[EE + e], 1);
}

__global__ __launch_bounds__(256)
void k_scan(const int* __restrict__ counts, int* __restrict__ rowptr, int* __restrict__ cursor) {
  const int CHUNK = (NN + 255) / 256;
  int t = threadIdx.x;
  int lo = t * CHUNK, hi = min(lo + CHUNK, NN);
  int s = 0;
  for (int i = lo; i < hi; ++i) s += counts[i];
  __shared__ int tsum[256];
  tsum[t] = s;
  __syncthreads();
  if (t == 0) {
    int run = 0;
    for (int i = 0; i < 256; ++i) { int v = tsum[i]; tsum[i] = run; run += v; }
  }
  __syncthreads();
  int run = tsum[t];
  for (int i = lo; i < hi; ++i) {
    rowptr[i] = run;
    cursor[i] = run;
    run += counts[i];
  }
  if (t == 255) rowptr[NN] = EE;
}

__global__ void k_fill(const int* __restrict__ ei, const float* __restrict__ ew,
                       int* __restrict__ cursor, int* __restrict__ colsrc,
                       float* __restrict__ ecw) {
  int e = blockIdx.x * blockDim.x + threadIdx.x;
  if (e < EE) {
    int d = ei[EE + e];
    int pos = atomicAdd(cursor + d, 1);
    colsrc[pos] = ei[e];
    ecw[pos] = ew[e];
  }
}

__global__ void k_degcsr(const int* __restrict__ rowptr, const float* __restrict__ ecw,
                         float* __restrict__ dinv, float* __restrict__ dinv2) {
  int i = blockIdx.x * blockDim.x + threadIdx.x;
  if (i < NN) {
    float s = 0.f;
    for (int e = rowptr[i]; e < rowptr[i + 1]; ++e) s += ecw[e];
    float d = s + 1.0f;
    dinv[i] = rsqrtf(d);
    dinv2[i] = 1.0f / d;
  }
}

// ---------------- bf16 MFMA GEMM: C[M,N] = A[M,K] @ BT[N,K]^T (+bias) ----------------
template <bool STORE_BF16, bool HAS_BIAS>
__global__ __launch_bounds__(256)
void k_mfma(const u16* __restrict__ A, const u16* __restrict__ BT,
            const float* __restrict__ bias, void* __restrict__ C,
            int M, int K, int N) {
  __shared__ u16 Asm[128 * 32];
  __shared__ u16 Bsm[128 * 32];
  const int tid = threadIdx.x;
  const int m0 = blockIdx.x * 128;
  const int n0 = blockIdx.y * 128;
  const int lane = tid & 63;
  const int wave = tid >> 6;
  const int wm = (wave >> 1) * 64;
  const int wn = (wave & 1) * 64;
  const int qm = lane & 15;
  const int quad = lane >> 4;

  f32x4 acc[4][4];
#pragma unroll
  for (int i = 0; i < 4; ++i)
#pragma unroll
    for (int j = 0; j < 4; ++j) acc[i][j] = (f32x4){0.f, 0.f, 0.f, 0.f};

  for (int k0 = 0; k0 < K; k0 += 32) {
#pragma unroll
    for (int h = 0; h < 2; ++h) {
      int c = h * 256 + tid;
      int row = c >> 2, kc = c & 3;
      gload16(A + (size_t)(m0 + row) * K + k0 + kc * 8, Asm + c * 8);
      gload16(BT + (size_t)(n0 + row) * K + k0 + kc * 8, Bsm + c * 8);
    }
    __syncthreads();
    short8 af[4], bfr[4];
#pragma unroll
    for (int i = 0; i < 4; ++i)
      af[i] = *(const short8*)(Asm + (wm + i * 16 + qm) * 32 + quad * 8);
#pragma unroll
    for (int j = 0; j < 4; ++j)
      bfr[j] = *(const short8*)(Bsm + (wn + j * 16 + qm) * 32 + quad * 8);
#pragma unroll
    for (int i = 0; i < 4; ++i)
#pragma unroll
      for (int j = 0; j < 4; ++j)
        acc[i][j] = __builtin_amdgcn_mfma_f32_16x16x32_bf16(af[i], bfr[j], acc[i][j], 0, 0, 0);
    __syncthreads();
  }

#pragma unroll
  for (int i = 0; i < 4; ++i) {
#pragma unroll
    for (int r = 0; r < 4; ++r) {
      int row = m0 + wm + i * 16 + quad * 4 + r;
      if (row >= M) continue;
#pragma unroll
      for (int j = 0; j < 4; ++j) {
        int col = n0 + wn + j * 16 + qm;
        float v = acc[i][j][r];
        if (HAS_BIAS) v += bias[col];
        if (STORE_BF16) ((u16*)C)[(size_t)row * N + col] = f2b(v);
        else ((float*)C)[(size_t)row * N + col] = v;
      }
    }
  }
}

// ---------------- dual-head MFMA + fused z-pooling, coalesced LDS-transpose epilogue ----------------
// A[M,256] @ {WmuT,WlvT}[512,256]^T; stores mu/lv fp32 (float4), computes
// z = mu + 0.01*eps*exp(0.5*beta*lv), per-(m-tile,col) max/sum partials.
__global__ __launch_bounds__(256)
void k_heads(const u16* __restrict__ A, const u16* __restrict__ BmuT,
             const u16* __restrict__ BlvT, const float* __restrict__ bmu,
             const float* __restrict__ blv, const float* __restrict__ eps,
             const float* __restrict__ beta_p, float* __restrict__ mu_out,
             float* __restrict__ lv_out, float* __restrict__ pmax,
             float* __restrict__ psum) {
  const int K = 256;
  __shared__ float smemf[8704];  // 34816 B, aliased across phases
  u16* Asm = (u16*)smemf;                    // [0, 8192)
  u16* Bmu = (u16*)((char*)smemf + 8192);    // [8192, 16384)
  u16* Blv = (u16*)((char*)smemf + 16384);   // [16384, 24576)
  float* stmu = smemf;                       // 32*132 floats = 16896 B
  float* stlv = smemf + 32 * 132;            // another 16896 B (total 33792)
  const int tid = threadIdx.x;
  const int m0 = blockIdx.x * 128;
  const int n0 = blockIdx.y * 128;
  const int lane = tid & 63;
  const int wave = tid >> 6;
  const int wn = (wave & 1) * 64;
  const int qm = lane & 15;
  const int quad = lane >> 4;

  f32x4 am[4][4], al[4][4];
#pragma unroll
  for (int i = 0; i < 4; ++i)
#pragma unroll
    for (int j = 0; j < 4; ++j) {
      am[i][j] = (f32x4){0.f, 0.f, 0.f, 0.f};
      al[i][j] = (f32x4){0.f, 0.f, 0.f, 0.f};
    }

  const int wm = (wave >> 1) * 64;
  for (int k0 = 0; k0 < K; k0 += 32) {
#pragma unroll
    for (int h = 0; h < 2; ++h) {
      int c = h * 256 + tid;
      int row = c >> 2, kc = c & 3;
      gload16(A + (size_t)(m0 + row) * K + k0 + kc * 8, Asm + c * 8);
      gload16(BmuT + (size_t)(n0 + row) * K + k0 + kc * 8, Bmu + c * 8);
      gload16(BlvT + (size_t)(n0 + row) * K + k0 + kc * 8, Blv + c * 8);
    }
    __syncthreads();
    short8 af[4], bm[4], bl[4];
#pragma unroll
    for (int i = 0; i < 4; ++i)
      af[i] = *(const short8*)(Asm + (wm + i * 16 + qm) * 32 + quad * 8);
#pragma unroll
    for (int j = 0; j < 4; ++j) {
      bm[j] = *(const short8*)(Bmu + (wn + j * 16 + qm) * 32 + quad * 8);
      bl[j] = *(const short8*)(Blv + (wn + j * 16 + qm) * 32 + quad * 8);
    }
#pragma unroll
    for (int i = 0; i < 4; ++i)
#pragma unroll
      for (int j = 0; j < 4; ++j) {
        am[i][j] = __builtin_amdgcn_mfma_f32_16x16x32_bf16(af[i], bm[j], am[i][j], 0, 0, 0);
        al[i][j] = __builtin_amdgcn_mfma_f32_16x16x32_bf16(af[i], bl[j], al[i][j], 0, 0, 0);
      }
    __syncthreads();
  }

  const float beta = beta_p[0];
  float biasm[4], biasl[4];
#pragma unroll
  for (int j = 0; j < 4; ++j) {
    int col = n0 + wn + j * 16 + qm;
    biasm[j] = bmu[col];
    biasl[j] = blv[col];
  }

  // per-thread pool partials over 16 fixed columns
  float zmax[16], zsum[16];
#pragma unroll
  for (int q = 0; q < 16; ++q) { zmax[q] = -3.4e38f; zsum[q] = 0.f; }
  const int lrow_r = tid >> 3;        // 0..31
  const int colb = (tid & 7) * 16;    // 0..112

  for (int c = 0; c < 4; ++c) {
    __syncthreads();
    if ((wave >> 1) == (c >> 1)) {
      int ibase = (c & 1) * 2;
#pragma unroll
      for (int ii = 0; ii < 2; ++ii) {
        int i = ibase + ii;
#pragma unroll
        for (int j = 0; j < 4; ++j) {
          int lcol = wn + j * 16 + qm;
#pragma unroll
          for (int r = 0; r < 4; ++r) {
            int lr = ii * 16 + quad * 4 + r;
            stmu[lr * 132 + lcol] = am[i][j][r] + biasm[j];
            stlv[lr * 132 + lcol] = al[i][j][r] + biasl[j];
          }
        }
      }
    }
    __syncthreads();
    int grow = m0 + c * 32 + lrow_r;
    if (grow < NN) {
#pragma unroll
      for (int q = 0; q < 4; ++q) {
        int lcol = colb + q * 4;
        float4 m4 = *(float4*)(stmu + lrow_r * 132 + lcol);
        float4 l4 = *(float4*)(stlv + lrow_r * 132 + lcol);
        size_t gidx = (size_t)grow * 512 + n0 + lcol;
        float4 e4 = *(const float4*)(eps + gidx);
        *(float4*)(mu_out + gidx) = m4;
        *(float4*)(lv_out + gidx) = l4;
        float z0 = m4.x + 0.01f * e4.x * expf(0.5f * beta * l4.x);
        float z1 = m4.y + 0.01f * e4.y * expf(0.5f * beta * l4.y);
        float z2 = m4.z + 0.01f * e4.z * expf(0.5f * beta * l4.z);
        float z3 = m4.w + 0.01f * e4.w * expf(0.5f * beta * l4.w);
        zmax[q * 4 + 0] = fmaxf(zmax[q * 4 + 0], z0); zsum[q * 4 + 0] += z0;
        zmax[q * 4 + 1] = fmaxf(zmax[q * 4 + 1], z1); zsum[q * 4 + 1] += z1;
        zmax[q * 4 + 2] = fmaxf(zmax[q * 4 + 2], z2); zsum[q * 4 + 2] += z2;
        zmax[q * 4 + 3] = fmaxf(zmax[q * 4 + 3], z3); zsum[q * 4 + 3] += z3;
      }
    }
  }

  // pool reduction: 32 threads share each 16-col group
  __syncthreads();
  float* rbuf = smemf;  // 256*32 floats = 32768 B
#pragma unroll
  for (int q = 0; q < 16; ++q) {
    rbuf[tid * 32 + q] = zmax[q];
    rbuf[tid * 32 + 16 + q] = zsum[q];
  }
  __syncthreads();
  if (tid < 128) {
    int colgroup = tid >> 4, coff = tid & 15;
    float m = -3.4e38f, s = 0.f;
    for (int k = 0; k < 32; ++k) {
      int src = (k * 8 + colgroup) * 32;
      m = fmaxf(m, rbuf[src + coff]);
      s += rbuf[src + 16 + coff];
    }
    pmax[(size_t)blockIdx.x * 512 + n0 + tid] = m;
    psum[(size_t)blockIdx.x * 512 + n0 + tid] = s;
  }
}

// rz[1025] = [max-pool | mean-pool | y_target], reducing MTILES partials
__global__ void k_zred(const float* __restrict__ pmax, const float* __restrict__ psum,
                       const float* __restrict__ yt, float* __restrict__ rz) {
  int col = threadIdx.x;  // 512 threads
  float m = -3.4e38f, s = 0.f;
  for (int c = 0; c < MTILES; ++c) {
    m = fmaxf(m, pmax[(size_t)c * 512 + col]);
    s += psum[(size_t)c * 512 + col];
  }
  rz[col] = m;
  rz[512 + col] = s / (float)NN;
  if (col == 0) rz[1024] = yt[0];
}

// ---------------- fused CSR gather (bf16 in/out), O = 2*NT ----------------
template <int NT, bool PRE>
__global__ __launch_bounds__(NT)
void k_gather(const int* __restrict__ rowptr, const int* __restrict__ colsrc,
              const float* __restrict__ ecw, const float* __restrict__ dinv,
              const float* __restrict__ dinv2, const u16* __restrict__ xw,
              const float* __restrict__ bias, u16* __restrict__ h) {
  const int O = 2 * NT;
  const int row = blockIdx.x;
  const int tid = threadIdx.x;
  const float dv = dinv[row], dv2 = dinv2[row];
  u32 u = ((const u32*)(xw + (size_t)row * O))[tid];
  float a0 = dv2 * bf16lo(u);
  float a1 = dv2 * bf16hi(u);
  if (!PRE) { a0 += bias[2 * tid]; a1 += bias[2 * tid + 1]; }

  __shared__ int s_src[NT];
  __shared__ float s_w[NT];
  const int e0 = rowptr[row], e1 = rowptr[row + 1];
  for (int base = e0; base < e1; base += NT) {
    int cnt = min(NT, e1 - base);
    __syncthreads();
    if (tid < cnt) {
      int s = colsrc[base + tid];
      s_src[tid] = s;
      s_w[tid] = dinv[s] * ecw[base + tid] * dv;
    }
    __syncthreads();
    for (int e = 0; e < cnt; ++e) {
      float w = s_w[e];
      u32 v = ((const u32*)(xw + (size_t)s_src[e] * O))[tid];
      a0 += w * bf16lo(v);
      a1 += w * bf16hi(v);
    }
  }

  if (PRE) {
    ((u32*)h)[(size_t)row * NT + tid] = pack2(a0, a1);
    return;
  }
  float ss = a0 * a0 + a1 * a1;
#pragma unroll
  for (int off = 32; off > 0; off >>= 1) ss += __shfl_down(ss, off, 64);
  __shared__ float red[NT / 64];
  __shared__ float s_scale;
  if ((tid & 63) == 0) red[tid >> 6] = ss;
  __syncthreads();
  if (tid == 0) {
    float t = 0.f;
#pragma unroll
    for (int i = 0; i < NT / 64; ++i) t += red[i];
    s_scale = 1.0f / fmaxf(sqrtf(t), 1e-12f);
  }
  __syncthreads();
  float sc = s_scale;
  ((u32*)h)[(size_t)row * NT + tid] = pack2(fmaxf(a0 * sc, 0.f), fmaxf(a1 * sc, 0.f));
}

// ---------------- rowwise l2norm + relu, bf16 in/out, O=1024 ----------------
__global__ __launch_bounds__(256)
void k_l2relu(const u16* __restrict__ t, u16* __restrict__ h) {
  const int row = blockIdx.x;
  const int tid = threadIdx.x;
  const u32* tr = (const u32*)(t + (size_t)row * 1024);
  u32 u0 = tr[tid], u1 = tr[256 + tid];
  float a0 = bf16lo(u0), a1 = bf16hi(u0), a2 = bf16lo(u1), a3 = bf16hi(u1);
  float ss = a0 * a0 + a1 * a1 + a2 * a2 + a3 * a3;
#pragma unroll
  for (int off = 32; off > 0; off >>= 1) ss += __shfl_down(ss, off, 64);
  __shared__ float red[4];
  __shared__ float s_scale;
  if ((tid & 63) == 0) red[tid >> 6] = ss;
  __syncthreads();
  if (tid == 0) {
    float s = red[0] + red[1] + red[2] + red[3];
    s_scale = 1.0f / fmaxf(sqrtf(s), 1e-12f);
  }
  __syncthreads();
  float sc = s_scale;
  u32* hr = (u32*)(h + (size_t)row * 1024);
  hr[tid]       = pack2(fmaxf(a0 * sc, 0.f), fmaxf(a1 * sc, 0.f));
  hr[256 + tid] = pack2(fmaxf(a2 * sc, 0.f), fmaxf(a3 * sc, 0.f));
}

// ---------------- parallel decoder ----------------
__global__ __launch_bounds__(256)
void k_dec_partial(const float* __restrict__ v, const float* __restrict__ W,
                   float* __restrict__ partial, int Kdim, int Ndim) {
  int b = blockIdx.x;
  int lo = b * DCH;
  float rv[DCH];
#pragma unroll
  for (int j = 0; j < DCH; ++j) rv[j] = (lo + j < Kdim) ? v[lo + j] : 0.f;
  for (int n = threadIdx.x; n < Ndim; n += 256) {
    float s = 0.f;
#pragma unroll
    for (int j = 0; j < DCH; ++j)
      if (lo + j < Kdim) s += rv[j] * W[(size_t)(lo + j) * Ndim + n];
    partial[(size_t)b * Ndim + n] = s;
  }
}

template <int ACT>
__global__ __launch_bounds__(256)
void k_dec_combine(const float* __restrict__ partial, const float* __restrict__ bias,
                   float* __restrict__ out, int Ndim) {
  int n = blockIdx.x * 256 + threadIdx.x;
  if (n >= Ndim) return;
  float s = bias[n];
  for (int b = 0; b < DKB; ++b) s += partial[(size_t)b * Ndim + n];
  out[n] = (ACT == 0) ? fmaxf(s, 0.f) : 1.0f / (1.0f + expf(-s));
}

extern "C" void kernel_launch(void* const* d_in, const int* in_sizes, int n_in,
                              void* d_out, int out_size, void* d_ws, size_t ws_size,
                              hipStream_t stream) {
  const float* x    = (const float*)d_in[0];
  const int*   ei   = (const int*)d_in[1];
  const float* ew   = (const float*)d_in[2];
  const float* beta = (const float*)d_in[3];
  const float* yt   = (const float*)d_in[4];
  const float* eps  = (const float*)d_in[5];
  const float* W1   = (const float*)d_in[6];  const float* b1  = (const float*)d_in[7];
  const float* W2   = (const float*)d_in[8];  const float* b2  = (const float*)d_in[9];
  const float* W3   = (const float*)d_in[10]; const float* b3  = (const float*)d_in[11];
  const float* Wmu  = (const float*)d_in[12]; const float* bmu = (const float*)d_in[13];
  const float* Wlv  = (const float*)d_in[14]; const float* blv = (const float*)d_in[15];
  const float* Wd1  = (const float*)d_in[16]; const float* bd1 = (const float*)d_in[17];
  const float* Wd2  = (const float*)d_in[18]; const float* bd2 = (const float*)d_in[19];

  char* wsb = (char*)d_ws;
  size_t off = 0;
  auto alloc_f = [&](size_t n) { float* p = (float*)(wsb + off); off += n * sizeof(float); return p; };
  auto alloc_i = [&](size_t n) { int* p = (int*)(wsb + off); off += n * sizeof(int); return p; };
  auto alloc_h = [&](size_t n) { u16* p = (u16*)(wsb + off); off += ((n * 2 + 3) & ~(size_t)3); return p; };

  int* counts  = alloc_i(NN);
  int* rowptr  = alloc_i(NN + 1);
  int* cursor  = alloc_i(NN);
  int* colsrc  = alloc_i(EE);
  float* ecw   = alloc_f(EE);
  float* dinv  = alloc_f(NN);
  float* din2  = alloc_f(NN);
  float* pmax  = alloc_f((size_t)MTILES * 512);
  float* psum  = alloc_f((size_t)MTILES * 512);
  float* rz    = alloc_f(1028);
  float* hdec  = alloc_f(1028);
  float* part1 = alloc_f((size_t)DKB * 1025);
  float* part2 = alloc_f((size_t)DKB * 1024);
  u16* W1T  = alloc_h(1024 * 512);
  u16* W2T  = alloc_h(512 * 1024);
  u16* W3T  = alloc_h(256 * 512);
  u16* WmuT = alloc_h(512 * 256);
  u16* WlvT = alloc_h(512 * 256);
  u16* xb   = alloc_h((size_t)MPAD * 512);   // x bf16; later reused as h3 (256)
  u16* aggx = alloc_h((size_t)MPAD * 512);   // pre-aggregated x
  u16* bufT = alloc_h((size_t)MPAD * 1024);  // t1; later z2 (512)
  u16* bufH = alloc_h((size_t)MPAD * 1024);  // h1; later z3 (256)
  u16* h2   = alloc_h((size_t)MPAD * 512);
  u16* h3   = xb;
  u16* z2   = bufT;
  u16* z3   = bufH;

  float* out_f  = (float*)d_out;
  float* mu_out = out_f + 1024;
  float* lv_out = out_f + 1024 + (size_t)NN * 512;

  const int MT = MTILES;

  // ---- casts / transposes ----
  k_f2b2<<<4096, 256, 0, stream>>>(x, xb, NN * 512 / 2);
  k_wt_all<<<5632, 256, 0, stream>>>(W1, W2, W3, Wmu, Wlv, W1T, W2T, W3T, WmuT, WlvT);

  // ---- CSR build + degree norms ----
  k_zeroi<<<(NN + 255) / 256, 256, 0, stream>>>(counts, NN);
  k_count<<<(EE + 255) / 256, 256, 0, stream>>>(ei, counts);
  k_scan<<<1, 256, 0, stream>>>(counts, rowptr, cursor);
  k_fill<<<(EE + 255) / 256, 256, 0, stream>>>(ei, ew, cursor, colsrc, ecw);
  k_degcsr<<<(NN + 255) / 256, 256, 0, stream>>>(rowptr, ecw, dinv, din2);

  // ---- layer 1: aggregate x first (linearity), then GEMM+bias, then l2relu ----
  k_gather<256, true><<<NN, 256, 0, stream>>>(rowptr, colsrc, ecw, dinv, din2, xb, nullptr, aggx);
  k_mfma<true, true><<<dim3(MT, 8), 256, 0, stream>>>(aggx, W1T, b1, bufT, NN, 512, 1024);
  k_l2relu<<<NN, 256, 0, stream>>>(bufT, bufH);

  // ---- layer 2: GEMM then fused gather+bias+l2relu ----
  k_mfma<true, false><<<dim3(MT, 4), 256, 0, stream>>>(bufH, W2T, nullptr, z2, NN, 1024, 512);
  k_gather<256, false><<<NN, 256, 0, stream>>>(rowptr, colsrc, ecw, dinv, din2, z2, b2, h2);

  // ---- layer 3 ----
  k_mfma<true, false><<<dim3(MT, 2), 256, 0, stream>>>(h2, W3T, nullptr, z3, NN, 512, 256);
  k_gather<128, false><<<NN, 128, 0, stream>>>(rowptr, colsrc, ecw, dinv, din2, z3, b3, h3);

  // ---- fused VAE heads + reparameterize + partial pooling ----
  k_heads<<<dim3(MT, 4), 256, 0, stream>>>(h3, WmuT, WlvT, bmu, blv, eps, beta,
                                           mu_out, lv_out, pmax, psum);
  k_zred<<<1, 512, 0, stream>>>(pmax, psum, yt, rz);

  // ---- parallel decoder ----
  k_dec_partial<<<DKB, 256, 0, stream>>>(rz, Wd1, part1, 1025, 1025);
  k_dec_combine<0><<<5, 256, 0, stream>>>(part1, bd1, hdec, 1025);
  k_dec_partial<<<DKB, 256, 0, stream>>>(hdec, Wd2, part2, 1025, 1024);
  k_dec_combine<1><<<4, 256, 0, stream>>>(part2, bd2, out_f, 1024);
}